// Round 2
// baseline (1002.417 us; speedup 1.0000x reference)
//
#include <hip/hip_runtime.h>

#define EMB 128
#define W1LD 532  // PRED_IN

// bf16 round-to-nearest-even helpers (manual, no API dependence)
__device__ __forceinline__ unsigned short f2bf(float x) {
    unsigned u = __float_as_uint(x);
    unsigned r = (u + 0x7fffu + ((u >> 16) & 1u)) >> 16;
    return (unsigned short)r;
}

// ---------------------------------------------------------------------------
// DDE scatter-mean kernels
// dde1[t] = mean_{e: t_id[e]==t} topic[h_id[e]]       (forward round 1)
// dde2[t] = mean_{e: t_id[e]==t} dde1[h_id[e]]        (forward round 2)
// dde3[h] = mean_{e: h_id[e]==h} topic[t_id[e]]       (reverse round 1)
// dde4[h] = mean_{e: h_id[e]==h} dde3[t_id[e]]        (reverse round 2)
// ---------------------------------------------------------------------------

__global__ __launch_bounds__(256) void scatter_round1(
    const int* __restrict__ h_id, const int* __restrict__ t_id,
    const float* __restrict__ topic,
    float* __restrict__ cnt_t, float* __restrict__ cnt_h,
    float* __restrict__ dde1, float* __restrict__ dde3, int E)
{
    int e = blockIdx.x * 256 + threadIdx.x;
    if (e >= E) return;
    int h = h_id[e], t = t_id[e];
    atomicAdd(&cnt_t[t], 1.0f);
    atomicAdd(&cnt_h[h], 1.0f);
    float2 th = *(const float2*)(topic + 2 * h);
    atomicAdd(&dde1[2 * t + 0], th.x);
    atomicAdd(&dde1[2 * t + 1], th.y);
    float2 tt = *(const float2*)(topic + 2 * t);
    atomicAdd(&dde3[2 * h + 0], tt.x);
    atomicAdd(&dde3[2 * h + 1], tt.y);
}

__global__ __launch_bounds__(256) void finalize_pair(
    float* __restrict__ da, const float* __restrict__ ca,
    float* __restrict__ db, const float* __restrict__ cb, int N)
{
    int n = blockIdx.x * 256 + threadIdx.x;
    if (n >= N) return;
    float ia = 1.0f / fmaxf(ca[n], 1.0f);
    float ib = 1.0f / fmaxf(cb[n], 1.0f);
    da[2 * n + 0] *= ia;
    da[2 * n + 1] *= ia;
    db[2 * n + 0] *= ib;
    db[2 * n + 1] *= ib;
}

__global__ __launch_bounds__(256) void scatter_round2(
    const int* __restrict__ h_id, const int* __restrict__ t_id,
    const float* __restrict__ dde1, const float* __restrict__ dde3,
    float* __restrict__ dde2, float* __restrict__ dde4, int E)
{
    int e = blockIdx.x * 256 + threadIdx.x;
    if (e >= E) return;
    int h = h_id[e], t = t_id[e];
    float2 v1 = *(const float2*)(dde1 + 2 * h);
    atomicAdd(&dde2[2 * t + 0], v1.x);
    atomicAdd(&dde2[2 * t + 1], v1.y);
    float2 v3 = *(const float2*)(dde3 + 2 * t);
    atomicAdd(&dde4[2 * h + 0], v3.x);
    atomicAdd(&dde4[2 * h + 1], v3.y);
}

// ---------------------------------------------------------------------------
// qWb[j] = sum_k q[k] * W1[j, k] + b1[j]            (q block, cols 0:128)
// R[r][j] = sum_k rel[r,k] * W1[j, 266+k]           (relation block, 266:394)
// block 0 -> qWb, block b>=1 -> relation b-1
// ---------------------------------------------------------------------------

__global__ __launch_bounds__(128) void qr_pre(
    const float* __restrict__ q, const float* __restrict__ rel,
    const float* __restrict__ W1, const float* __restrict__ b1,
    float* __restrict__ qWb, float* __restrict__ R, int NREL)
{
    __shared__ float v[EMB];
    int j = threadIdx.x;
    int b = blockIdx.x;
    const float* src   = (b == 0) ? q   : rel + (size_t)(b - 1) * EMB;
    const float* wbase = (b == 0) ? W1  : W1 + 266;
    float* dst         = (b == 0) ? qWb : R + (size_t)(b - 1) * EMB;
    v[j] = src[j];
    __syncthreads();
    const float* w = wbase + (size_t)j * W1LD;
    float s = 0.0f;
#pragma unroll 4
    for (int k = 0; k < EMB; k++) s += v[k] * w[k];
    if (b == 0) s += b1[j];
    dst[j] = s;
}

// Copy the t-side weight block W1[:, 394:532] into an aligned [128][140]
// scratch so the node kernel can do aligned float4 reads.
__global__ void wb_prep(const float* __restrict__ W1, float* __restrict__ WB)
{
    int j = blockIdx.x;      // 0..127
    int k = threadIdx.x;     // 0..143
    if (k < 138) WB[j * 140 + k] = W1[(size_t)j * W1LD + 394 + k];
}

// ---------------------------------------------------------------------------
// Node kernel: for every node n and hidden unit j:
//   A[n][j] = qWb[j] + sum_{k<138} feat[n][k] * W1[j, 128+k]   (h-side block)
//   B[n][j] =          sum_{k<138} feat[n][k] * WB[j][k]       (t-side block)
// feat[n] = [h_e(n) (128), topic(n) (2), dde1..4(n) (2 each)]
// h-side cols 128:266 of W1 are contiguous: dense 128:256, tail 256:266. ✓
// 8 nodes per block, 128 threads (thread = output column j).
// ---------------------------------------------------------------------------

__global__ __launch_bounds__(128) void node_ab(
    const float* __restrict__ ent, const float* __restrict__ nte,
    const float* __restrict__ topic, const float* __restrict__ dde,
    const float* __restrict__ W1, const float* __restrict__ WB,
    const float* __restrict__ qWb,
    unsigned short* __restrict__ A, unsigned short* __restrict__ B,
    int NT, int N)
{
    __shared__ float fs[8][144];
    const int j = threadIdx.x;        // output column 0..127
    const int n0 = blockIdx.x * 8;

    // stage dense feature part: fs[m][j]
#pragma unroll
    for (int m = 0; m < 8; m++) {
        int gn = n0 + m;
        float v = 0.0f;
        if (gn < N) v = (gn < NT) ? ent[(size_t)gn * EMB + j] : nte[j];
        fs[m][j] = v;
    }
    // stage tail (topic + 4 dde pairs): fs[m][128+mm]
    if (j < 80) {
        int m = j / 10, mm = j - m * 10;
        int gn = n0 + m;
        float v = 0.0f;
        if (gn < N) {
            if (mm < 2) v = topic[2 * gn + mm];
            else {
                int d = mm - 2;
                v = dde[(size_t)(d >> 1) * 2 * N + 2 * gn + (d & 1)];
            }
        }
        fs[m][EMB + mm] = v;
    }
    __syncthreads();

    float accA[8], accB[8];
    const float qv = qWb[j];
#pragma unroll
    for (int m = 0; m < 8; m++) { accA[m] = qv; accB[m] = 0.0f; }

    const float* wa = W1 + (size_t)j * W1LD + 128;  // cols 128..265, contiguous
    const float* wb = WB + (size_t)j * 140;

    for (int k = 0; k < 136; k += 4) {
        float4 wa4 = *(const float4*)(wa + k);
        float4 wb4 = *(const float4*)(wb + k);
#pragma unroll
        for (int m = 0; m < 8; m++) {
            float4 f = *(const float4*)&fs[m][k];
            accA[m] += wa4.x * f.x + wa4.y * f.y + wa4.z * f.z + wa4.w * f.w;
            accB[m] += wb4.x * f.x + wb4.y * f.y + wb4.z * f.z + wb4.w * f.w;
        }
    }
    {   // k = 136,137
        float2 wa2 = *(const float2*)(wa + 136);
        float2 wb2 = *(const float2*)(wb + 136);
#pragma unroll
        for (int m = 0; m < 8; m++) {
            float2 f = *(const float2*)&fs[m][136];
            accA[m] += wa2.x * f.x + wa2.y * f.y;
            accB[m] += wb2.x * f.x + wb2.y * f.y;
        }
    }

#pragma unroll
    for (int m = 0; m < 8; m++) {
        int gn = n0 + m;
        if (gn >= N) continue;
        A[(size_t)gn * EMB + j] = f2bf(accA[m]);
        B[(size_t)gn * EMB + j] = f2bf(accB[m]);
    }
}

// ---------------------------------------------------------------------------
// Edge kernel: pred[e] = W2 . relu(A[h] + R[r] + B[t]) + b2
// One wave per edge, 2 elems/lane, butterfly reduce.
// ---------------------------------------------------------------------------

__global__ __launch_bounds__(256) void edge_pred(
    const int* __restrict__ h_id, const int* __restrict__ r_id,
    const int* __restrict__ t_id,
    const unsigned short* __restrict__ A, const unsigned short* __restrict__ B,
    const float* __restrict__ R,
    const float* __restrict__ W2, const float* __restrict__ b2,
    float* __restrict__ out, int E)
{
    int wid = (blockIdx.x * 256 + threadIdx.x) >> 6;
    int lane = threadIdx.x & 63;
    if (wid >= E) return;
    int h = h_id[wid], r = r_id[wid], t = t_id[wid];

    unsigned ua = *(const unsigned*)(A + (size_t)h * EMB + 2 * lane);
    unsigned ub = *(const unsigned*)(B + (size_t)t * EMB + 2 * lane);
    float a0 = __uint_as_float(ua << 16);
    float a1 = __uint_as_float(ua & 0xffff0000u);
    float b0 = __uint_as_float(ub << 16);
    float b1v = __uint_as_float(ub & 0xffff0000u);

    float2 rr = *(const float2*)(R  + (size_t)r * EMB + 2 * lane);
    float2 w  = *(const float2*)(W2 + 2 * lane);

    float s = fmaxf(a0 + rr.x + b0, 0.0f) * w.x
            + fmaxf(a1 + rr.y + b1v, 0.0f) * w.y;
#pragma unroll
    for (int off = 32; off > 0; off >>= 1) s += __shfl_xor(s, off, 64);
    if (lane == 0) out[wid] = s + b2[0];
}

// ---------------------------------------------------------------------------

extern "C" void kernel_launch(void* const* d_in, const int* in_sizes, int n_in,
                              void* d_out, int out_size, void* d_ws, size_t ws_size,
                              hipStream_t stream)
{
    const int*   h_id  = (const int*)d_in[0];
    const int*   r_id  = (const int*)d_in[1];
    const int*   t_id  = (const int*)d_in[2];
    const float* q_emb = (const float*)d_in[3];
    const float* ent   = (const float*)d_in[4];
    const float* rel   = (const float*)d_in[6];
    const float* topic = (const float*)d_in[7];
    const float* nte   = (const float*)d_in[8];
    const float* W1    = (const float*)d_in[9];
    const float* b1    = (const float*)d_in[10];
    const float* W2    = (const float*)d_in[11];
    const float* b2    = (const float*)d_in[12];

    const int E    = in_sizes[0];
    const int NT   = in_sizes[4] / EMB;  // 80000 text entities
    const int N    = in_sizes[7] / 2;    // 100000 total nodes
    const int NREL = in_sizes[6] / EMB;  // 500 relations

    // workspace layout (floats)
    float* ws    = (float*)d_ws;
    float* cnt_t = ws;                        // N
    float* cnt_h = cnt_t + N;                 // N
    float* dde   = cnt_h + N;                 // 8N  (dde1..dde4, 2N each)
    float* dde1  = dde + (size_t)0 * 2 * N;
    float* dde2  = dde + (size_t)1 * 2 * N;
    float* dde3  = dde + (size_t)2 * 2 * N;
    float* dde4  = dde + (size_t)3 * 2 * N;
    float* qWb   = dde + (size_t)8 * N;       // 128
    float* Rw    = qWb + EMB;                 // NREL*128
    float* WB    = Rw + (size_t)NREL * EMB;   // 128*140
    unsigned short* Aw = (unsigned short*)(WB + 128 * 140);  // N*128 bf16
    unsigned short* Bw = Aw + (size_t)N * EMB;               // N*128 bf16

    // zero the atomic-accumulated region (counts + dde sums)
    hipMemsetAsync(d_ws, 0, sizeof(float) * (size_t)(10 * N), stream);

    const int tb = 256;
    scatter_round1<<<(E + tb - 1) / tb, tb, 0, stream>>>(
        h_id, t_id, topic, cnt_t, cnt_h, dde1, dde3, E);
    finalize_pair<<<(N + tb - 1) / tb, tb, 0, stream>>>(dde1, cnt_t, dde3, cnt_h, N);
    scatter_round2<<<(E + tb - 1) / tb, tb, 0, stream>>>(
        h_id, t_id, dde1, dde3, dde2, dde4, E);
    finalize_pair<<<(N + tb - 1) / tb, tb, 0, stream>>>(dde2, cnt_t, dde4, cnt_h, N);

    qr_pre<<<NREL + 1, 128, 0, stream>>>(q_emb, rel, W1, b1, qWb, Rw, NREL);
    wb_prep<<<128, 144, 0, stream>>>(W1, WB);

    node_ab<<<(N + 7) / 8, 128, 0, stream>>>(ent, nte, topic, dde, W1, WB, qWb,
                                             Aw, Bw, NT, N);

    edge_pred<<<(E + 3) / 4, 256, 0, stream>>>(h_id, r_id, t_id, Aw, Bw, Rw,
                                               W2, b2, (float*)d_out, E);
}

// Round 3
// 770.779 us; speedup vs baseline: 1.3005x; 1.3005x over previous
//
#include <hip/hip_runtime.h>

#define EMB 128
#define W1LD 532  // PRED_IN

// bf16 round-to-nearest-even
__device__ __forceinline__ unsigned short f2bf(float x) {
    unsigned u = __float_as_uint(x);
    unsigned r = (u + 0x7fffu + ((u >> 16) & 1u)) >> 16;
    return (unsigned short)r;
}

// ---------------------------------------------------------------------------
// DDE scatter-mean kernels
// ---------------------------------------------------------------------------

__global__ __launch_bounds__(256) void scatter_round1(
    const int* __restrict__ h_id, const int* __restrict__ t_id,
    const float* __restrict__ topic,
    float* __restrict__ cnt_t, float* __restrict__ cnt_h,
    float* __restrict__ dde1, float* __restrict__ dde3, int E)
{
    int e = blockIdx.x * 256 + threadIdx.x;
    if (e >= E) return;
    int h = h_id[e], t = t_id[e];
    atomicAdd(&cnt_t[t], 1.0f);
    atomicAdd(&cnt_h[h], 1.0f);
    float2 th = *(const float2*)(topic + 2 * h);
    atomicAdd(&dde1[2 * t + 0], th.x);
    atomicAdd(&dde1[2 * t + 1], th.y);
    float2 tt = *(const float2*)(topic + 2 * t);
    atomicAdd(&dde3[2 * h + 0], tt.x);
    atomicAdd(&dde3[2 * h + 1], tt.y);
}

__global__ __launch_bounds__(256) void finalize_pair(
    float* __restrict__ da, const float* __restrict__ ca,
    float* __restrict__ db, const float* __restrict__ cb, int N)
{
    int n = blockIdx.x * 256 + threadIdx.x;
    if (n >= N) return;
    float ia = 1.0f / fmaxf(ca[n], 1.0f);
    float ib = 1.0f / fmaxf(cb[n], 1.0f);
    da[2 * n + 0] *= ia;
    da[2 * n + 1] *= ia;
    db[2 * n + 0] *= ib;
    db[2 * n + 1] *= ib;
}

__global__ __launch_bounds__(256) void scatter_round2(
    const int* __restrict__ h_id, const int* __restrict__ t_id,
    const float* __restrict__ dde1, const float* __restrict__ dde3,
    float* __restrict__ dde2, float* __restrict__ dde4, int E)
{
    int e = blockIdx.x * 256 + threadIdx.x;
    if (e >= E) return;
    int h = h_id[e], t = t_id[e];
    float2 v1 = *(const float2*)(dde1 + 2 * h);
    atomicAdd(&dde2[2 * t + 0], v1.x);
    atomicAdd(&dde2[2 * t + 1], v1.y);
    float2 v3 = *(const float2*)(dde3 + 2 * t);
    atomicAdd(&dde4[2 * h + 0], v3.x);
    atomicAdd(&dde4[2 * h + 1], v3.y);
}

// ---------------------------------------------------------------------------
// Weight transpose prep:
//   WT [138][256] : c<128 -> W1[c, 128+k]  (h-side), c>=128 -> W1[c-128, 394+k] (t-side)
//   WTQ[128][128] : WTQ[k][j] = W1[j, k]        (q block)
//   WTR[128][128] : WTR[k][j] = W1[j, 266+k]    (relation block)
// blocks 0..137 -> WT row k=bid ; blocks 138..265 -> WTQ/WTR row k=bid-138
// ---------------------------------------------------------------------------

__global__ __launch_bounds__(256) void wt_prep(
    const float* __restrict__ W1, float* __restrict__ WT,
    float* __restrict__ WTQ, float* __restrict__ WTR)
{
    int bid = blockIdx.x, t = threadIdx.x;
    if (bid < 138) {
        int k = bid;
        float v = (t < 128) ? W1[(size_t)t * W1LD + 128 + k]
                            : W1[(size_t)(t - 128) * W1LD + 394 + k];
        WT[(size_t)k * 256 + t] = v;
    } else {
        int k = bid - 138;
        if (t < 128) WTQ[(size_t)k * 128 + t] = W1[(size_t)t * W1LD + k];
        else         WTR[(size_t)k * 128 + (t - 128)] =
                         W1[(size_t)(t - 128) * W1LD + 266 + k];
    }
}

// ---------------------------------------------------------------------------
// qWb[j] = sum_k q[k]*W1[j,k] + b1[j] ; R[r][j] = sum_k rel[r,k]*W1[j,266+k]
// block 0 -> qWb, block b>=1 -> relation b-1. Coalesced via WTQ/WTR.
// ---------------------------------------------------------------------------

__global__ __launch_bounds__(128) void qr_pre(
    const float* __restrict__ q, const float* __restrict__ rel,
    const float* __restrict__ WTQ, const float* __restrict__ WTR,
    const float* __restrict__ b1,
    float* __restrict__ qWb, float* __restrict__ R, int NREL)
{
    __shared__ float v[EMB];
    int j = threadIdx.x;
    int b = blockIdx.x;
    const float* src = (b == 0) ? q   : rel + (size_t)(b - 1) * EMB;
    const float* wt  = (b == 0) ? WTQ : WTR;
    float* dst       = (b == 0) ? qWb : R + (size_t)(b - 1) * EMB;
    v[j] = src[j];
    __syncthreads();
    float s = 0.0f;
#pragma unroll 4
    for (int k = 0; k < EMB; k++) s += v[k] * wt[(size_t)k * 128 + j];
    if (b == 0) s += b1[j];
    dst[j] = s;
}

// ---------------------------------------------------------------------------
// Node kernel v2: register-tiled GEMM  [32 nodes x 138] @ WT[138 x 256]
// feat[n] = [h_e(n) (128), topic(2), dde1..4 (2 each)]
// Block: 256 threads. jt = t&63 -> cols 4jt..4jt+3 ; mt = t>>6 -> nodes mt*8+i.
// Weight reads coalesced float4 from WT; feature reads are wave-uniform
// LDS broadcasts (conflict-free). Output cols <128 -> A (+qWb), >=128 -> B.
// ---------------------------------------------------------------------------

__global__ __launch_bounds__(256) void node_ab(
    const float* __restrict__ ent, const float* __restrict__ nte,
    const float* __restrict__ topic, const float* __restrict__ dde,
    const float* __restrict__ WT, const float* __restrict__ qWb,
    unsigned short* __restrict__ A, unsigned short* __restrict__ B,
    int NT, int N)
{
    __shared__ float fs[32][140];   // [node][k], row stride 140 (16B-aligned rows)
    const int t  = threadIdx.x;
    const int jt = t & 63;          // col group: cols 4*jt .. 4*jt+3
    const int mt = t >> 6;          // node group: nodes mt*8 .. mt*8+7
    const int n0 = blockIdx.x * 32;

    // ---- stage dense features: 32 nodes x 128 floats, float4 coalesced ----
#pragma unroll
    for (int p = 0; p < 4; p++) {
        int idx = p * 256 + t;          // 0..1023
        int m   = idx >> 5;             // node 0..31
        int kq  = (idx & 31) << 2;      // 0,4,...,124
        int gn  = n0 + m;
        float4 v = make_float4(0.f, 0.f, 0.f, 0.f);
        if (gn < N) {
            const float* src = (gn < NT) ? (ent + (size_t)gn * EMB + kq)
                                         : (nte + kq);
            v = *(const float4*)src;
        }
        *(float4*)&fs[m][kq] = v;
    }
    // ---- stage tail: 32 nodes x 10 (topic + dde1..4) ----
    for (int i = t; i < 320; i += 256) {
        int m  = i / 10;
        int mm = i - m * 10;
        int gn = n0 + m;
        float v = 0.0f;
        if (gn < N) {
            if (mm < 2) v = topic[2 * gn + mm];
            else {
                int d = mm - 2;
                v = dde[(size_t)(d >> 1) * 2 * N + 2 * gn + (d & 1)];
            }
        }
        fs[m][EMB + mm] = v;
    }
    __syncthreads();

    float4 acc[8];
#pragma unroll
    for (int i = 0; i < 8; i++) acc[i] = make_float4(0.f, 0.f, 0.f, 0.f);

    const float* wp = WT + 4 * jt;
    for (int k = 0; k < 136; k += 4) {
        float4 w0 = *(const float4*)(wp + (size_t)(k + 0) * 256);
        float4 w1 = *(const float4*)(wp + (size_t)(k + 1) * 256);
        float4 w2 = *(const float4*)(wp + (size_t)(k + 2) * 256);
        float4 w3 = *(const float4*)(wp + (size_t)(k + 3) * 256);
#pragma unroll
        for (int i = 0; i < 8; i++) {
            float4 f = *(const float4*)&fs[mt * 8 + i][k];
            acc[i].x += f.x * w0.x + f.y * w1.x + f.z * w2.x + f.w * w3.x;
            acc[i].y += f.x * w0.y + f.y * w1.y + f.z * w2.y + f.w * w3.y;
            acc[i].z += f.x * w0.z + f.y * w1.z + f.z * w2.z + f.w * w3.z;
            acc[i].w += f.x * w0.w + f.y * w1.w + f.z * w2.w + f.w * w3.w;
        }
    }
    {   // k = 136, 137
        float4 w0 = *(const float4*)(wp + (size_t)136 * 256);
        float4 w1 = *(const float4*)(wp + (size_t)137 * 256);
#pragma unroll
        for (int i = 0; i < 8; i++) {
            float2 f = *(const float2*)&fs[mt * 8 + i][136];
            acc[i].x += f.x * w0.x + f.y * w1.x;
            acc[i].y += f.x * w0.y + f.y * w1.y;
            acc[i].z += f.x * w0.z + f.y * w1.z;
            acc[i].w += f.x * w0.w + f.y * w1.w;
        }
    }

    // ---- epilogue: cols <128 -> A (+qWb), cols >=128 -> B ; bf16 pack ----
    const bool isA = (jt < 32);
    float4 qv = make_float4(0.f, 0.f, 0.f, 0.f);
    if (isA) qv = *(const float4*)(qWb + 4 * jt);
#pragma unroll
    for (int i = 0; i < 8; i++) {
        int gn = n0 + mt * 8 + i;
        if (gn >= N) continue;
        float4 r = acc[i];
        unsigned short p0, p1, p2, p3;
        if (isA) {
            p0 = f2bf(r.x + qv.x); p1 = f2bf(r.y + qv.y);
            p2 = f2bf(r.z + qv.z); p3 = f2bf(r.w + qv.w);
            unsigned short* dst = A + (size_t)gn * EMB + 4 * jt;
            uint2 pk; pk.x = (unsigned)p0 | ((unsigned)p1 << 16);
            pk.y = (unsigned)p2 | ((unsigned)p3 << 16);
            *(uint2*)dst = pk;
        } else {
            p0 = f2bf(r.x); p1 = f2bf(r.y); p2 = f2bf(r.z); p3 = f2bf(r.w);
            unsigned short* dst = B + (size_t)gn * EMB + (4 * jt - 128);
            uint2 pk; pk.x = (unsigned)p0 | ((unsigned)p1 << 16);
            pk.y = (unsigned)p2 | ((unsigned)p3 << 16);
            *(uint2*)dst = pk;
        }
    }
}

// ---------------------------------------------------------------------------
// Edge kernel: pred[e] = W2 . relu(A[h] + R[r] + B[t]) + b2
// One wave per edge, 2 elems/lane, butterfly reduce.
// ---------------------------------------------------------------------------

__global__ __launch_bounds__(256) void edge_pred(
    const int* __restrict__ h_id, const int* __restrict__ r_id,
    const int* __restrict__ t_id,
    const unsigned short* __restrict__ A, const unsigned short* __restrict__ B,
    const float* __restrict__ R,
    const float* __restrict__ W2, const float* __restrict__ b2,
    float* __restrict__ out, int E)
{
    int wid = (blockIdx.x * 256 + threadIdx.x) >> 6;
    int lane = threadIdx.x & 63;
    if (wid >= E) return;
    int h = h_id[wid], r = r_id[wid], t = t_id[wid];

    unsigned ua = *(const unsigned*)(A + (size_t)h * EMB + 2 * lane);
    unsigned ub = *(const unsigned*)(B + (size_t)t * EMB + 2 * lane);
    float a0 = __uint_as_float(ua << 16);
    float a1 = __uint_as_float(ua & 0xffff0000u);
    float b0 = __uint_as_float(ub << 16);
    float b1v = __uint_as_float(ub & 0xffff0000u);

    float2 rr = *(const float2*)(R  + (size_t)r * EMB + 2 * lane);
    float2 w  = *(const float2*)(W2 + 2 * lane);

    float s = fmaxf(a0 + rr.x + b0, 0.0f) * w.x
            + fmaxf(a1 + rr.y + b1v, 0.0f) * w.y;
#pragma unroll
    for (int off = 32; off > 0; off >>= 1) s += __shfl_xor(s, off, 64);
    if (lane == 0) out[wid] = s + b2[0];
}

// ---------------------------------------------------------------------------

extern "C" void kernel_launch(void* const* d_in, const int* in_sizes, int n_in,
                              void* d_out, int out_size, void* d_ws, size_t ws_size,
                              hipStream_t stream)
{
    const int*   h_id  = (const int*)d_in[0];
    const int*   r_id  = (const int*)d_in[1];
    const int*   t_id  = (const int*)d_in[2];
    const float* q_emb = (const float*)d_in[3];
    const float* ent   = (const float*)d_in[4];
    const float* rel   = (const float*)d_in[6];
    const float* topic = (const float*)d_in[7];
    const float* nte   = (const float*)d_in[8];
    const float* W1    = (const float*)d_in[9];
    const float* b1    = (const float*)d_in[10];
    const float* W2    = (const float*)d_in[11];
    const float* b2    = (const float*)d_in[12];

    const int E    = in_sizes[0];
    const int NT   = in_sizes[4] / EMB;  // 80000 text entities
    const int N    = in_sizes[7] / 2;    // 100000 total nodes
    const int NREL = in_sizes[6] / EMB;  // 500 relations

    // workspace layout (floats)
    float* ws    = (float*)d_ws;
    float* cnt_t = ws;                        // N
    float* cnt_h = cnt_t + N;                 // N
    float* dde   = cnt_h + N;                 // 8N (dde1..4, 2N each)
    float* dde1  = dde + (size_t)0 * 2 * N;
    float* dde2  = dde + (size_t)1 * 2 * N;
    float* dde3  = dde + (size_t)2 * 2 * N;
    float* dde4  = dde + (size_t)3 * 2 * N;
    float* qWb   = dde + (size_t)8 * N;       // 128
    float* Rw    = qWb + EMB;                 // NREL*128
    float* WT    = Rw + (size_t)NREL * EMB;   // 138*256
    float* WTQ   = WT + 138 * 256;            // 128*128
    float* WTR   = WTQ + 128 * 128;           // 128*128
    unsigned short* Aw = (unsigned short*)(WTR + 128 * 128); // N*128 bf16
    unsigned short* Bw = Aw + (size_t)N * EMB;               // N*128 bf16

    // zero the atomic-accumulated region (counts + dde sums)
    hipMemsetAsync(d_ws, 0, sizeof(float) * (size_t)(10 * N), stream);

    const int tb = 256;
    scatter_round1<<<(E + tb - 1) / tb, tb, 0, stream>>>(
        h_id, t_id, topic, cnt_t, cnt_h, dde1, dde3, E);
    finalize_pair<<<(N + tb - 1) / tb, tb, 0, stream>>>(dde1, cnt_t, dde3, cnt_h, N);
    scatter_round2<<<(E + tb - 1) / tb, tb, 0, stream>>>(
        h_id, t_id, dde1, dde3, dde2, dde4, E);
    finalize_pair<<<(N + tb - 1) / tb, tb, 0, stream>>>(dde2, cnt_t, dde4, cnt_h, N);

    wt_prep<<<266, 256, 0, stream>>>(W1, WT, WTQ, WTR);
    qr_pre<<<NREL + 1, 128, 0, stream>>>(q_emb, rel, WTQ, WTR, b1, qWb, Rw, NREL);

    node_ab<<<(N + 31) / 32, 256, 0, stream>>>(ent, nte, topic, dde, WT, qWb,
                                               Aw, Bw, NT, N);

    edge_pred<<<(E + 3) / 4, 256, 0, stream>>>(h_id, r_id, t_id, Aw, Bw, Rw,
                                               W2, b2, (float*)d_out, E);
}

// Round 5
// 520.870 us; speedup vs baseline: 1.9245x; 1.4798x over previous
//
#include <hip/hip_runtime.h>

#define EMB 128
#define W1LD 532  // PRED_IN

typedef unsigned long long u64;

// bf16 round-to-nearest-even
__device__ __forceinline__ unsigned short f2bf(float x) {
    unsigned u = __float_as_uint(x);
    unsigned r = (u + 0x7fffu + ((u >> 16) & 1u)) >> 16;
    return (unsigned short)r;
}

// ---------------------------------------------------------------------------
// DDE scatter-mean via packed u64 atomics.
// Round 1 pack: [x*2^13 : 21b][y*2^13 : 21b][count : 22b]
//   values in [0,1); max degree << 256 so fields never carry across.
// Round 2 pack: [x*2^20 : 32b][y*2^20 : 32b]
// ---------------------------------------------------------------------------

__global__ __launch_bounds__(256) void scatter1_packed(
    const int* __restrict__ h_id, const int* __restrict__ t_id,
    const float* __restrict__ topic,
    u64* __restrict__ acc_t, u64* __restrict__ acc_h, int E)
{
    int e = blockIdx.x * 256 + threadIdx.x;
    if (e >= E) return;
    int h = h_id[e], t = t_id[e];
    float2 th = *(const float2*)(topic + 2 * h);
    float2 tt = *(const float2*)(topic + 2 * t);
    u64 p1 = (u64)__float2uint_rn(th.x * 8192.0f)
           | ((u64)__float2uint_rn(th.y * 8192.0f) << 21)
           | (1ull << 42);
    u64 p3 = (u64)__float2uint_rn(tt.x * 8192.0f)
           | ((u64)__float2uint_rn(tt.y * 8192.0f) << 21)
           | (1ull << 42);
    atomicAdd(&acc_t[t], p1);
    atomicAdd(&acc_h[h], p3);
}

// unpack round-1 accumulators -> dde1/dde3 (means) + float counts
__global__ __launch_bounds__(256) void unpack1(
    const u64* __restrict__ acc_t, const u64* __restrict__ acc_h,
    float* __restrict__ dde1, float* __restrict__ dde3,
    float* __restrict__ cnt_t, float* __restrict__ cnt_h, int N)
{
    int n = blockIdx.x * 256 + threadIdx.x;
    if (n >= N) return;
    const float is = 1.0f / 8192.0f;
    u64 a = acc_t[n];
    float cx = (float)(a >> 42);
    float ia = is / fmaxf(cx, 1.0f);
    dde1[2 * n + 0] = (float)(a & 0x1FFFFFull) * ia;
    dde1[2 * n + 1] = (float)((a >> 21) & 0x1FFFFFull) * ia;
    cnt_t[n] = cx;
    u64 b = acc_h[n];
    float cy = (float)(b >> 42);
    float ib = is / fmaxf(cy, 1.0f);
    dde3[2 * n + 0] = (float)(b & 0x1FFFFFull) * ib;
    dde3[2 * n + 1] = (float)((b >> 21) & 0x1FFFFFull) * ib;
    cnt_h[n] = cy;
}

__global__ __launch_bounds__(256) void scatter2_packed(
    const int* __restrict__ h_id, const int* __restrict__ t_id,
    const float* __restrict__ dde1, const float* __restrict__ dde3,
    u64* __restrict__ acc2_t, u64* __restrict__ acc2_h, int E)
{
    int e = blockIdx.x * 256 + threadIdx.x;
    if (e >= E) return;
    int h = h_id[e], t = t_id[e];
    float2 v1 = *(const float2*)(dde1 + 2 * h);
    float2 v3 = *(const float2*)(dde3 + 2 * t);
    const float sc = 1048576.0f;  // 2^20
    u64 p2 = (u64)__float2uint_rn(v1.x * sc)
           | ((u64)__float2uint_rn(v1.y * sc) << 32);
    u64 p4 = (u64)__float2uint_rn(v3.x * sc)
           | ((u64)__float2uint_rn(v3.y * sc) << 32);
    atomicAdd(&acc2_t[t], p2);
    atomicAdd(&acc2_h[h], p4);
}

__global__ __launch_bounds__(256) void unpack2(
    const u64* __restrict__ acc2_t, const u64* __restrict__ acc2_h,
    const float* __restrict__ cnt_t, const float* __restrict__ cnt_h,
    float* __restrict__ dde2, float* __restrict__ dde4, int N)
{
    int n = blockIdx.x * 256 + threadIdx.x;
    if (n >= N) return;
    const float is = 1.0f / 1048576.0f;
    u64 a = acc2_t[n];
    float ia = is / fmaxf(cnt_t[n], 1.0f);
    dde2[2 * n + 0] = (float)(a & 0xFFFFFFFFull) * ia;
    dde2[2 * n + 1] = (float)(a >> 32) * ia;
    u64 b = acc2_h[n];
    float ib = is / fmaxf(cnt_h[n], 1.0f);
    dde4[2 * n + 0] = (float)(b & 0xFFFFFFFFull) * ib;
    dde4[2 * n + 1] = (float)(b >> 32) * ib;
}

// ---------------------------------------------------------------------------
// Weight transpose prep:
//   WT [138][256] : c<128 -> W1[c, 128+k]  (h-side), c>=128 -> W1[c-128, 394+k]
//   WTQ[128][128] : WTQ[k][j] = W1[j, k]        (q block)
//   WTR[128][128] : WTR[k][j] = W1[j, 266+k]    (relation block)
// ---------------------------------------------------------------------------

__global__ __launch_bounds__(256) void wt_prep(
    const float* __restrict__ W1, float* __restrict__ WT,
    float* __restrict__ WTQ, float* __restrict__ WTR)
{
    int bid = blockIdx.x, t = threadIdx.x;
    if (bid < 138) {
        int k = bid;
        float v = (t < 128) ? W1[(size_t)t * W1LD + 128 + k]
                            : W1[(size_t)(t - 128) * W1LD + 394 + k];
        WT[(size_t)k * 256 + t] = v;
    } else {
        int k = bid - 138;
        if (t < 128) WTQ[(size_t)k * 128 + t] = W1[(size_t)t * W1LD + k];
        else         WTR[(size_t)k * 128 + (t - 128)] =
                         W1[(size_t)(t - 128) * W1LD + 266 + k];
    }
}

// ---------------------------------------------------------------------------
// qWb[j] = sum_k q[k]*W1[j,k] + b1[j] ; R[r][j] = sum_k rel[r,k]*W1[j,266+k]
// ---------------------------------------------------------------------------

__global__ __launch_bounds__(128) void qr_pre(
    const float* __restrict__ q, const float* __restrict__ rel,
    const float* __restrict__ WTQ, const float* __restrict__ WTR,
    const float* __restrict__ b1,
    float* __restrict__ qWb, float* __restrict__ R, int NREL)
{
    __shared__ float v[EMB];
    int j = threadIdx.x;
    int b = blockIdx.x;
    const float* src = (b == 0) ? q   : rel + (size_t)(b - 1) * EMB;
    const float* wt  = (b == 0) ? WTQ : WTR;
    float* dst       = (b == 0) ? qWb : R + (size_t)(b - 1) * EMB;
    v[j] = src[j];
    __syncthreads();
    float s = 0.0f;
#pragma unroll 4
    for (int k = 0; k < EMB; k++) s += v[k] * wt[(size_t)k * 128 + j];
    if (b == 0) s += b1[j];
    dst[j] = s;
}

// ---------------------------------------------------------------------------
// Node kernel: register-tiled GEMM  [32 nodes x 138] @ WT[138 x 256]
// ---------------------------------------------------------------------------

__global__ __launch_bounds__(256) void node_ab(
    const float* __restrict__ ent, const float* __restrict__ nte,
    const float* __restrict__ topic, const float* __restrict__ dde,
    const float* __restrict__ WT, const float* __restrict__ qWb,
    unsigned short* __restrict__ A, unsigned short* __restrict__ B,
    int NT, int N)
{
    __shared__ float fs[32][140];
    const int t  = threadIdx.x;
    const int jt = t & 63;
    const int mt = t >> 6;
    const int n0 = blockIdx.x * 32;

#pragma unroll
    for (int p = 0; p < 4; p++) {
        int idx = p * 256 + t;
        int m   = idx >> 5;
        int kq  = (idx & 31) << 2;
        int gn  = n0 + m;
        float4 v = make_float4(0.f, 0.f, 0.f, 0.f);
        if (gn < N) {
            const float* src = (gn < NT) ? (ent + (size_t)gn * EMB + kq)
                                         : (nte + kq);
            v = *(const float4*)src;
        }
        *(float4*)&fs[m][kq] = v;
    }
    for (int i = t; i < 320; i += 256) {
        int m  = i / 10;
        int mm = i - m * 10;
        int gn = n0 + m;
        float v = 0.0f;
        if (gn < N) {
            if (mm < 2) v = topic[2 * gn + mm];
            else {
                int d = mm - 2;
                v = dde[(size_t)(d >> 1) * 2 * N + 2 * gn + (d & 1)];
            }
        }
        fs[m][EMB + mm] = v;
    }
    __syncthreads();

    float4 acc[8];
#pragma unroll
    for (int i = 0; i < 8; i++) acc[i] = make_float4(0.f, 0.f, 0.f, 0.f);

    const float* wp = WT + 4 * jt;
    for (int k = 0; k < 136; k += 4) {
        float4 w0 = *(const float4*)(wp + (size_t)(k + 0) * 256);
        float4 w1 = *(const float4*)(wp + (size_t)(k + 1) * 256);
        float4 w2 = *(const float4*)(wp + (size_t)(k + 2) * 256);
        float4 w3 = *(const float4*)(wp + (size_t)(k + 3) * 256);
#pragma unroll
        for (int i = 0; i < 8; i++) {
            float4 f = *(const float4*)&fs[mt * 8 + i][k];
            acc[i].x += f.x * w0.x + f.y * w1.x + f.z * w2.x + f.w * w3.x;
            acc[i].y += f.x * w0.y + f.y * w1.y + f.z * w2.y + f.w * w3.y;
            acc[i].z += f.x * w0.z + f.y * w1.z + f.z * w2.z + f.w * w3.z;
            acc[i].w += f.x * w0.w + f.y * w1.w + f.z * w2.w + f.w * w3.w;
        }
    }
    {
        float4 w0 = *(const float4*)(wp + (size_t)136 * 256);
        float4 w1 = *(const float4*)(wp + (size_t)137 * 256);
#pragma unroll
        for (int i = 0; i < 8; i++) {
            float2 f = *(const float2*)&fs[mt * 8 + i][136];
            acc[i].x += f.x * w0.x + f.y * w1.x;
            acc[i].y += f.x * w0.y + f.y * w1.y;
            acc[i].z += f.x * w0.z + f.y * w1.z;
            acc[i].w += f.x * w0.w + f.y * w1.w;
        }
    }

    const bool isA = (jt < 32);
    float4 qv = make_float4(0.f, 0.f, 0.f, 0.f);
    if (isA) qv = *(const float4*)(qWb + 4 * jt);
#pragma unroll
    for (int i = 0; i < 8; i++) {
        int gn = n0 + mt * 8 + i;
        if (gn >= N) continue;
        float4 r = acc[i];
        unsigned short p0, p1, p2, p3;
        if (isA) {
            p0 = f2bf(r.x + qv.x); p1 = f2bf(r.y + qv.y);
            p2 = f2bf(r.z + qv.z); p3 = f2bf(r.w + qv.w);
            unsigned short* dst = A + (size_t)gn * EMB + 4 * jt;
            uint2 pk; pk.x = (unsigned)p0 | ((unsigned)p1 << 16);
            pk.y = (unsigned)p2 | ((unsigned)p3 << 16);
            *(uint2*)dst = pk;
        } else {
            p0 = f2bf(r.x); p1 = f2bf(r.y); p2 = f2bf(r.z); p3 = f2bf(r.w);
            unsigned short* dst = B + (size_t)gn * EMB + (4 * jt - 128);
            uint2 pk; pk.x = (unsigned)p0 | ((unsigned)p1 << 16);
            pk.y = (unsigned)p2 | ((unsigned)p3 << 16);
            *(uint2*)dst = pk;
        }
    }
}

// ---------------------------------------------------------------------------
// Edge kernel: pred[e] = W2 . relu(A[h] + R[r] + B[t]) + b2
// ---------------------------------------------------------------------------

__global__ __launch_bounds__(256) void edge_pred(
    const int* __restrict__ h_id, const int* __restrict__ r_id,
    const int* __restrict__ t_id,
    const unsigned short* __restrict__ A, const unsigned short* __restrict__ B,
    const float* __restrict__ R,
    const float* __restrict__ W2, const float* __restrict__ b2,
    float* __restrict__ out, int E)
{
    int wid = (blockIdx.x * 256 + threadIdx.x) >> 6;
    int lane = threadIdx.x & 63;
    if (wid >= E) return;
    int h = h_id[wid], r = r_id[wid], t = t_id[wid];

    unsigned ua = *(const unsigned*)(A + (size_t)h * EMB + 2 * lane);
    unsigned ub = *(const unsigned*)(B + (size_t)t * EMB + 2 * lane);
    float a0 = __uint_as_float(ua << 16);
    float a1 = __uint_as_float(ua & 0xffff0000u);
    float b0 = __uint_as_float(ub << 16);
    float b1v = __uint_as_float(ub & 0xffff0000u);

    float2 rr = *(const float2*)(R  + (size_t)r * EMB + 2 * lane);
    float2 w  = *(const float2*)(W2 + 2 * lane);

    float s = fmaxf(a0 + rr.x + b0, 0.0f) * w.x
            + fmaxf(a1 + rr.y + b1v, 0.0f) * w.y;
#pragma unroll
    for (int off = 32; off > 0; off >>= 1) s += __shfl_xor(s, off, 64);
    if (lane == 0) out[wid] = s + b2[0];
}

// ---------------------------------------------------------------------------

extern "C" void kernel_launch(void* const* d_in, const int* in_sizes, int n_in,
                              void* d_out, int out_size, void* d_ws, size_t ws_size,
                              hipStream_t stream)
{
    const int*   h_id  = (const int*)d_in[0];
    const int*   r_id  = (const int*)d_in[1];
    const int*   t_id  = (const int*)d_in[2];
    const float* q_emb = (const float*)d_in[3];
    const float* ent   = (const float*)d_in[4];
    const float* rel   = (const float*)d_in[6];
    const float* topic = (const float*)d_in[7];
    const float* nte   = (const float*)d_in[8];
    const float* W1    = (const float*)d_in[9];
    const float* b1    = (const float*)d_in[10];
    const float* W2    = (const float*)d_in[11];
    const float* b2    = (const float*)d_in[12];

    const int E    = in_sizes[0];
    const int NT   = in_sizes[4] / EMB;  // 80000 text entities
    const int N    = in_sizes[7] / 2;    // 100000 total nodes
    const int NREL = in_sizes[6] / EMB;  // 500 relations

    // workspace layout
    u64* acc1_t = (u64*)d_ws;                 // N u64
    u64* acc1_h = acc1_t + N;                 // N u64
    u64* acc2_t = acc1_h + N;                 // N u64
    u64* acc2_h = acc2_t + N;                 // N u64
    float* cnt_t = (float*)(acc2_h + N);      // N
    float* cnt_h = cnt_t + N;                 // N
    float* dde   = cnt_h + N;                 // 8N (dde1..4, 2N each)
    float* dde1  = dde + (size_t)0 * 2 * N;
    float* dde2  = dde + (size_t)1 * 2 * N;
    float* dde3  = dde + (size_t)2 * 2 * N;
    float* dde4  = dde + (size_t)3 * 2 * N;
    float* qWb   = dde + (size_t)8 * N;       // 128
    float* Rw    = qWb + EMB;                 // NREL*128
    float* WT    = Rw + (size_t)NREL * EMB;   // 138*256
    float* WTQ   = WT + 138 * 256;            // 128*128
    float* WTR   = WTQ + 128 * 128;           // 128*128
    unsigned short* Aw = (unsigned short*)(WTR + 128 * 128); // N*128 bf16
    unsigned short* Bw = Aw + (size_t)N * EMB;               // N*128 bf16

    // zero only the packed atomic accumulators (4N u64)
    hipMemsetAsync(d_ws, 0, sizeof(u64) * (size_t)(4 * N), stream);

    const int tb = 256;
    scatter1_packed<<<(E + tb - 1) / tb, tb, 0, stream>>>(
        h_id, t_id, topic, acc1_t, acc1_h, E);
    unpack1<<<(N + tb - 1) / tb, tb, 0, stream>>>(
        acc1_t, acc1_h, dde1, dde3, cnt_t, cnt_h, N);
    scatter2_packed<<<(E + tb - 1) / tb, tb, 0, stream>>>(
        h_id, t_id, dde1, dde3, acc2_t, acc2_h, E);
    unpack2<<<(N + tb - 1) / tb, tb, 0, stream>>>(
        acc2_t, acc2_h, cnt_t, cnt_h, dde2, dde4, N);

    wt_prep<<<266, 256, 0, stream>>>(W1, WT, WTQ, WTR);
    qr_pre<<<NREL + 1, 128, 0, stream>>>(q_emb, rel, WTQ, WTR, b1, qWb, Rw, NREL);

    node_ab<<<(N + 31) / 32, 256, 0, stream>>>(ent, nte, topic, dde, WT, qWb,
                                               Aw, Bw, NT, N);

    edge_pred<<<(E + 3) / 4, 256, 0, stream>>>(h_id, r_id, t_id, Aw, Bw, Rw,
                                               W2, b2, (float*)d_out, E);
}

// Round 6
// 436.858 us; speedup vs baseline: 2.2946x; 1.1923x over previous
//
#include <hip/hip_runtime.h>

#define EMB 128
#define W1LD 532  // PRED_IN

typedef unsigned long long u64;

// bf16 round-to-nearest-even
__device__ __forceinline__ unsigned short f2bf(float x) {
    unsigned u = __float_as_uint(x);
    unsigned r = (u + 0x7fffu + ((u >> 16) & 1u)) >> 16;
    return (unsigned short)r;
}

// ---------------------------------------------------------------------------
// DDE scatter-mean via packed u64 atomics.
// Round 1 pack: [x*2^13 : 21b][y*2^13 : 21b][count : 22b]
// Round 2 pack: [x*2^20 : 32b][y*2^20 : 32b]
// ---------------------------------------------------------------------------

__global__ __launch_bounds__(256) void scatter1_packed(
    const int* __restrict__ h_id, const int* __restrict__ t_id,
    const float* __restrict__ topic,
    u64* __restrict__ acc_t, u64* __restrict__ acc_h, int E)
{
    int e = blockIdx.x * 256 + threadIdx.x;
    if (e >= E) return;
    int h = h_id[e], t = t_id[e];
    float2 th = *(const float2*)(topic + 2 * h);
    float2 tt = *(const float2*)(topic + 2 * t);
    u64 p1 = (u64)__float2uint_rn(th.x * 8192.0f)
           | ((u64)__float2uint_rn(th.y * 8192.0f) << 21)
           | (1ull << 42);
    u64 p3 = (u64)__float2uint_rn(tt.x * 8192.0f)
           | ((u64)__float2uint_rn(tt.y * 8192.0f) << 21)
           | (1ull << 42);
    atomicAdd(&acc_t[t], p1);
    atomicAdd(&acc_h[h], p3);
}

__global__ __launch_bounds__(256) void unpack1(
    const u64* __restrict__ acc_t, const u64* __restrict__ acc_h,
    float* __restrict__ dde1, float* __restrict__ dde3,
    float* __restrict__ cnt_t, float* __restrict__ cnt_h, int N)
{
    int n = blockIdx.x * 256 + threadIdx.x;
    if (n >= N) return;
    const float is = 1.0f / 8192.0f;
    u64 a = acc_t[n];
    float cx = (float)(a >> 42);
    float ia = is / fmaxf(cx, 1.0f);
    dde1[2 * n + 0] = (float)(a & 0x1FFFFFull) * ia;
    dde1[2 * n + 1] = (float)((a >> 21) & 0x1FFFFFull) * ia;
    cnt_t[n] = cx;
    u64 b = acc_h[n];
    float cy = (float)(b >> 42);
    float ib = is / fmaxf(cy, 1.0f);
    dde3[2 * n + 0] = (float)(b & 0x1FFFFFull) * ib;
    dde3[2 * n + 1] = (float)((b >> 21) & 0x1FFFFFull) * ib;
    cnt_h[n] = cy;
}

__global__ __launch_bounds__(256) void scatter2_packed(
    const int* __restrict__ h_id, const int* __restrict__ t_id,
    const float* __restrict__ dde1, const float* __restrict__ dde3,
    u64* __restrict__ acc2_t, u64* __restrict__ acc2_h, int E)
{
    int e = blockIdx.x * 256 + threadIdx.x;
    if (e >= E) return;
    int h = h_id[e], t = t_id[e];
    float2 v1 = *(const float2*)(dde1 + 2 * h);
    float2 v3 = *(const float2*)(dde3 + 2 * t);
    const float sc = 1048576.0f;  // 2^20
    u64 p2 = (u64)__float2uint_rn(v1.x * sc)
           | ((u64)__float2uint_rn(v1.y * sc) << 32);
    u64 p4 = (u64)__float2uint_rn(v3.x * sc)
           | ((u64)__float2uint_rn(v3.y * sc) << 32);
    atomicAdd(&acc2_t[t], p2);
    atomicAdd(&acc2_h[h], p4);
}

__global__ __launch_bounds__(256) void unpack2(
    const u64* __restrict__ acc2_t, const u64* __restrict__ acc2_h,
    const float* __restrict__ cnt_t, const float* __restrict__ cnt_h,
    float* __restrict__ dde2, float* __restrict__ dde4, int N)
{
    int n = blockIdx.x * 256 + threadIdx.x;
    if (n >= N) return;
    const float is = 1.0f / 1048576.0f;
    u64 a = acc2_t[n];
    float ia = is / fmaxf(cnt_t[n], 1.0f);
    dde2[2 * n + 0] = (float)(a & 0xFFFFFFFFull) * ia;
    dde2[2 * n + 1] = (float)(a >> 32) * ia;
    u64 b = acc2_h[n];
    float ib = is / fmaxf(cnt_h[n], 1.0f);
    dde4[2 * n + 0] = (float)(b & 0xFFFFFFFFull) * ib;
    dde4[2 * n + 1] = (float)(b >> 32) * ib;
}

// ---------------------------------------------------------------------------
// Weight transpose prep
// ---------------------------------------------------------------------------

__global__ __launch_bounds__(256) void wt_prep(
    const float* __restrict__ W1, float* __restrict__ WT,
    float* __restrict__ WTQ, float* __restrict__ WTR)
{
    int bid = blockIdx.x, t = threadIdx.x;
    if (bid < 138) {
        int k = bid;
        float v = (t < 128) ? W1[(size_t)t * W1LD + 128 + k]
                            : W1[(size_t)(t - 128) * W1LD + 394 + k];
        WT[(size_t)k * 256 + t] = v;
    } else {
        int k = bid - 138;
        if (t < 128) WTQ[(size_t)k * 128 + t] = W1[(size_t)t * W1LD + k];
        else         WTR[(size_t)k * 128 + (t - 128)] =
                         W1[(size_t)(t - 128) * W1LD + 266 + k];
    }
}

// ---------------------------------------------------------------------------
// qWb / R precompute
// ---------------------------------------------------------------------------

__global__ __launch_bounds__(128) void qr_pre(
    const float* __restrict__ q, const float* __restrict__ rel,
    const float* __restrict__ WTQ, const float* __restrict__ WTR,
    const float* __restrict__ b1,
    float* __restrict__ qWb, float* __restrict__ R, int NREL)
{
    __shared__ float v[EMB];
    int j = threadIdx.x;
    int b = blockIdx.x;
    const float* src = (b == 0) ? q   : rel + (size_t)(b - 1) * EMB;
    const float* wt  = (b == 0) ? WTQ : WTR;
    float* dst       = (b == 0) ? qWb : R + (size_t)(b - 1) * EMB;
    v[j] = src[j];
    __syncthreads();
    float s = 0.0f;
#pragma unroll 4
    for (int k = 0; k < EMB; k++) s += v[k] * wt[(size_t)k * 128 + j];
    if (b == 0) s += b1[j];
    dst[j] = s;
}

// ---------------------------------------------------------------------------
// Node kernel: register-tiled GEMM  [32 nodes x 138] @ WT[138 x 256]
// ---------------------------------------------------------------------------

__global__ __launch_bounds__(256) void node_ab(
    const float* __restrict__ ent, const float* __restrict__ nte,
    const float* __restrict__ topic, const float* __restrict__ dde,
    const float* __restrict__ WT, const float* __restrict__ qWb,
    unsigned short* __restrict__ A, unsigned short* __restrict__ B,
    int NT, int N)
{
    __shared__ float fs[32][140];
    const int t  = threadIdx.x;
    const int jt = t & 63;
    const int mt = t >> 6;
    const int n0 = blockIdx.x * 32;

#pragma unroll
    for (int p = 0; p < 4; p++) {
        int idx = p * 256 + t;
        int m   = idx >> 5;
        int kq  = (idx & 31) << 2;
        int gn  = n0 + m;
        float4 v = make_float4(0.f, 0.f, 0.f, 0.f);
        if (gn < N) {
            const float* src = (gn < NT) ? (ent + (size_t)gn * EMB + kq)
                                         : (nte + kq);
            v = *(const float4*)src;
        }
        *(float4*)&fs[m][kq] = v;
    }
    for (int i = t; i < 320; i += 256) {
        int m  = i / 10;
        int mm = i - m * 10;
        int gn = n0 + m;
        float v = 0.0f;
        if (gn < N) {
            if (mm < 2) v = topic[2 * gn + mm];
            else {
                int d = mm - 2;
                v = dde[(size_t)(d >> 1) * 2 * N + 2 * gn + (d & 1)];
            }
        }
        fs[m][EMB + mm] = v;
    }
    __syncthreads();

    float4 acc[8];
#pragma unroll
    for (int i = 0; i < 8; i++) acc[i] = make_float4(0.f, 0.f, 0.f, 0.f);

    const float* wp = WT + 4 * jt;
    for (int k = 0; k < 136; k += 4) {
        float4 w0 = *(const float4*)(wp + (size_t)(k + 0) * 256);
        float4 w1 = *(const float4*)(wp + (size_t)(k + 1) * 256);
        float4 w2 = *(const float4*)(wp + (size_t)(k + 2) * 256);
        float4 w3 = *(const float4*)(wp + (size_t)(k + 3) * 256);
#pragma unroll
        for (int i = 0; i < 8; i++) {
            float4 f = *(const float4*)&fs[mt * 8 + i][k];
            acc[i].x += f.x * w0.x + f.y * w1.x + f.z * w2.x + f.w * w3.x;
            acc[i].y += f.x * w0.y + f.y * w1.y + f.z * w2.y + f.w * w3.y;
            acc[i].z += f.x * w0.z + f.y * w1.z + f.z * w2.z + f.w * w3.z;
            acc[i].w += f.x * w0.w + f.y * w1.w + f.z * w2.w + f.w * w3.w;
        }
    }
    {
        float4 w0 = *(const float4*)(wp + (size_t)136 * 256);
        float4 w1 = *(const float4*)(wp + (size_t)137 * 256);
#pragma unroll
        for (int i = 0; i < 8; i++) {
            float2 f = *(const float2*)&fs[mt * 8 + i][136];
            acc[i].x += f.x * w0.x + f.y * w1.x;
            acc[i].y += f.x * w0.y + f.y * w1.y;
            acc[i].z += f.x * w0.z + f.y * w1.z;
            acc[i].w += f.x * w0.w + f.y * w1.w;
        }
    }

    const bool isA = (jt < 32);
    float4 qv = make_float4(0.f, 0.f, 0.f, 0.f);
    if (isA) qv = *(const float4*)(qWb + 4 * jt);
#pragma unroll
    for (int i = 0; i < 8; i++) {
        int gn = n0 + mt * 8 + i;
        if (gn >= N) continue;
        float4 r = acc[i];
        unsigned short p0, p1, p2, p3;
        if (isA) {
            p0 = f2bf(r.x + qv.x); p1 = f2bf(r.y + qv.y);
            p2 = f2bf(r.z + qv.z); p3 = f2bf(r.w + qv.w);
            unsigned short* dst = A + (size_t)gn * EMB + 4 * jt;
            uint2 pk; pk.x = (unsigned)p0 | ((unsigned)p1 << 16);
            pk.y = (unsigned)p2 | ((unsigned)p3 << 16);
            *(uint2*)dst = pk;
        } else {
            p0 = f2bf(r.x); p1 = f2bf(r.y); p2 = f2bf(r.z); p3 = f2bf(r.w);
            unsigned short* dst = B + (size_t)gn * EMB + (4 * jt - 128);
            uint2 pk; pk.x = (unsigned)p0 | ((unsigned)p1 << 16);
            pk.y = (unsigned)p2 | ((unsigned)p3 << 16);
            *(uint2*)dst = pk;
        }
    }
}

// ---------------------------------------------------------------------------
// Edge kernel v2: 16 lanes per edge, 8 elems/lane, 4 edges/wave.
// pred[e] = W2 . relu(A[h] + R[r] + B[t]) + b2
// Per lane: A,B via one uint4 (8 bf16) each; R via two float4; W2 slice
// register-resident (loop-invariant). Reduce: 4 shfl_xor within 16-lane group.
// ---------------------------------------------------------------------------

__global__ __launch_bounds__(256) void edge_pred(
    const int* __restrict__ h_id, const int* __restrict__ r_id,
    const int* __restrict__ t_id,
    const unsigned short* __restrict__ A, const unsigned short* __restrict__ B,
    const float* __restrict__ R,
    const float* __restrict__ W2, const float* __restrict__ b2,
    float* __restrict__ out, int E)
{
    const int t    = threadIdx.x;
    const int lane = t & 63;
    const int g    = lane >> 4;      // edge slot within wave (0..3)
    const int k    = lane & 15;      // element group: covers 8k..8k+7
    const int wv   = t >> 6;         // wave in block (0..3)
    const int e    = blockIdx.x * 16 + wv * 4 + g;

    // W2 slice: loop-invariant per thread
    const float4 w0 = *(const float4*)(W2 + k * 8);
    const float4 w1 = *(const float4*)(W2 + k * 8 + 4);

    float s = 0.0f;
    if (e < E) {
        const int h = h_id[e], r = r_id[e], tt = t_id[e];
        const uint4  ua = *(const uint4*)(A + (size_t)h * EMB + k * 8);
        const uint4  ub = *(const uint4*)(B + (size_t)tt * EMB + k * 8);
        const float* rp = R + (size_t)r * EMB + k * 8;
        const float4 r0 = *(const float4*)(rp);
        const float4 r1 = *(const float4*)(rp + 4);

        float a0 = __uint_as_float(ua.x << 16), a1 = __uint_as_float(ua.x & 0xffff0000u);
        float a2 = __uint_as_float(ua.y << 16), a3 = __uint_as_float(ua.y & 0xffff0000u);
        float a4 = __uint_as_float(ua.z << 16), a5 = __uint_as_float(ua.z & 0xffff0000u);
        float a6 = __uint_as_float(ua.w << 16), a7 = __uint_as_float(ua.w & 0xffff0000u);
        float c0 = __uint_as_float(ub.x << 16), c1 = __uint_as_float(ub.x & 0xffff0000u);
        float c2 = __uint_as_float(ub.y << 16), c3 = __uint_as_float(ub.y & 0xffff0000u);
        float c4 = __uint_as_float(ub.z << 16), c5 = __uint_as_float(ub.z & 0xffff0000u);
        float c6 = __uint_as_float(ub.w << 16), c7 = __uint_as_float(ub.w & 0xffff0000u);

        s  = fmaxf(a0 + r0.x + c0, 0.0f) * w0.x;
        s += fmaxf(a1 + r0.y + c1, 0.0f) * w0.y;
        s += fmaxf(a2 + r0.z + c2, 0.0f) * w0.z;
        s += fmaxf(a3 + r0.w + c3, 0.0f) * w0.w;
        s += fmaxf(a4 + r1.x + c4, 0.0f) * w1.x;
        s += fmaxf(a5 + r1.y + c5, 0.0f) * w1.y;
        s += fmaxf(a6 + r1.z + c6, 0.0f) * w1.z;
        s += fmaxf(a7 + r1.w + c7, 0.0f) * w1.w;
    }
    // reduce within 16-lane group (serves 4 edges per wave simultaneously)
    s += __shfl_xor(s, 1, 64);
    s += __shfl_xor(s, 2, 64);
    s += __shfl_xor(s, 4, 64);
    s += __shfl_xor(s, 8, 64);
    if (k == 0 && e < E) out[e] = s + b2[0];
}

// ---------------------------------------------------------------------------

extern "C" void kernel_launch(void* const* d_in, const int* in_sizes, int n_in,
                              void* d_out, int out_size, void* d_ws, size_t ws_size,
                              hipStream_t stream)
{
    const int*   h_id  = (const int*)d_in[0];
    const int*   r_id  = (const int*)d_in[1];
    const int*   t_id  = (const int*)d_in[2];
    const float* q_emb = (const float*)d_in[3];
    const float* ent   = (const float*)d_in[4];
    const float* rel   = (const float*)d_in[6];
    const float* topic = (const float*)d_in[7];
    const float* nte   = (const float*)d_in[8];
    const float* W1    = (const float*)d_in[9];
    const float* b1    = (const float*)d_in[10];
    const float* W2    = (const float*)d_in[11];
    const float* b2    = (const float*)d_in[12];

    const int E    = in_sizes[0];
    const int NT   = in_sizes[4] / EMB;  // 80000 text entities
    const int N    = in_sizes[7] / 2;    // 100000 total nodes
    const int NREL = in_sizes[6] / EMB;  // 500 relations

    // workspace layout
    u64* acc1_t = (u64*)d_ws;                 // N u64
    u64* acc1_h = acc1_t + N;                 // N u64
    u64* acc2_t = acc1_h + N;                 // N u64
    u64* acc2_h = acc2_t + N;                 // N u64
    float* cnt_t = (float*)(acc2_h + N);      // N
    float* cnt_h = cnt_t + N;                 // N
    float* dde   = cnt_h + N;                 // 8N (dde1..4, 2N each)
    float* dde1  = dde + (size_t)0 * 2 * N;
    float* dde2  = dde + (size_t)1 * 2 * N;
    float* dde3  = dde + (size_t)2 * 2 * N;
    float* dde4  = dde + (size_t)3 * 2 * N;
    float* qWb   = dde + (size_t)8 * N;       // 128
    float* Rw    = qWb + EMB;                 // NREL*128
    float* WT    = Rw + (size_t)NREL * EMB;   // 138*256
    float* WTQ   = WT + 138 * 256;            // 128*128
    float* WTR   = WTQ + 128 * 128;           // 128*128
    unsigned short* Aw = (unsigned short*)(WTR + 128 * 128); // N*128 bf16
    unsigned short* Bw = Aw + (size_t)N * EMB;               // N*128 bf16

    // zero only the packed atomic accumulators (4N u64)
    hipMemsetAsync(d_ws, 0, sizeof(u64) * (size_t)(4 * N), stream);

    const int tb = 256;
    scatter1_packed<<<(E + tb - 1) / tb, tb, 0, stream>>>(
        h_id, t_id, topic, acc1_t, acc1_h, E);
    unpack1<<<(N + tb - 1) / tb, tb, 0, stream>>>(
        acc1_t, acc1_h, dde1, dde3, cnt_t, cnt_h, N);
    scatter2_packed<<<(E + tb - 1) / tb, tb, 0, stream>>>(
        h_id, t_id, dde1, dde3, acc2_t, acc2_h, E);
    unpack2<<<(N + tb - 1) / tb, tb, 0, stream>>>(
        acc2_t, acc2_h, cnt_t, cnt_h, dde2, dde4, N);

    wt_prep<<<266, 256, 0, stream>>>(W1, WT, WTQ, WTR);
    qr_pre<<<NREL + 1, 128, 0, stream>>>(q_emb, rel, WTQ, WTR, b1, qWb, Rw, NREL);

    node_ab<<<(N + 31) / 32, 256, 0, stream>>>(ent, nte, topic, dde, WT, qWb,
                                               Aw, Bw, NT, N);

    edge_pred<<<(E + 15) / 16, 256, 0, stream>>>(h_id, r_id, t_id, Aw, Bw, Rw,
                                                 W2, b2, (float*)d_out, E);
}

// Round 7
// 363.382 us; speedup vs baseline: 2.7586x; 1.2022x over previous
//
#include <hip/hip_runtime.h>

#define EMB 128
#define W1LD 532  // PRED_IN
#define KP 160    // padded K for MFMA (138 -> 160)

typedef unsigned long long u64;
typedef __attribute__((ext_vector_type(8))) short short8;
typedef __attribute__((ext_vector_type(4))) float f32x4;

// bf16 round-to-nearest-even
__device__ __forceinline__ unsigned short f2bf(float x) {
    unsigned u = __float_as_uint(x);
    unsigned r = (u + 0x7fffu + ((u >> 16) & 1u)) >> 16;
    return (unsigned short)r;
}

// ---------------------------------------------------------------------------
// DDE scatter-mean via packed u64 atomics.
// Round 1 pack: [x*2^13 : 21b][y*2^13 : 21b][count : 22b]
// Round 2 pack: [x*2^20 : 32b][y*2^20 : 32b]
// ---------------------------------------------------------------------------

__global__ __launch_bounds__(256) void scatter1_packed(
    const int* __restrict__ h_id, const int* __restrict__ t_id,
    const float* __restrict__ topic,
    u64* __restrict__ acc_t, u64* __restrict__ acc_h, int E)
{
    int e = blockIdx.x * 256 + threadIdx.x;
    if (e >= E) return;
    int h = h_id[e], t = t_id[e];
    float2 th = *(const float2*)(topic + 2 * h);
    float2 tt = *(const float2*)(topic + 2 * t);
    u64 p1 = (u64)__float2uint_rn(th.x * 8192.0f)
           | ((u64)__float2uint_rn(th.y * 8192.0f) << 21)
           | (1ull << 42);
    u64 p3 = (u64)__float2uint_rn(tt.x * 8192.0f)
           | ((u64)__float2uint_rn(tt.y * 8192.0f) << 21)
           | (1ull << 42);
    atomicAdd(&acc_t[t], p1);
    atomicAdd(&acc_h[h], p3);
}

__global__ __launch_bounds__(256) void unpack1(
    const u64* __restrict__ acc_t, const u64* __restrict__ acc_h,
    float* __restrict__ dde1, float* __restrict__ dde3,
    float* __restrict__ cnt_t, float* __restrict__ cnt_h, int N)
{
    int n = blockIdx.x * 256 + threadIdx.x;
    if (n >= N) return;
    const float is = 1.0f / 8192.0f;
    u64 a = acc_t[n];
    float cx = (float)(a >> 42);
    float ia = is / fmaxf(cx, 1.0f);
    dde1[2 * n + 0] = (float)(a & 0x1FFFFFull) * ia;
    dde1[2 * n + 1] = (float)((a >> 21) & 0x1FFFFFull) * ia;
    cnt_t[n] = cx;
    u64 b = acc_h[n];
    float cy = (float)(b >> 42);
    float ib = is / fmaxf(cy, 1.0f);
    dde3[2 * n + 0] = (float)(b & 0x1FFFFFull) * ib;
    dde3[2 * n + 1] = (float)((b >> 21) & 0x1FFFFFull) * ib;
    cnt_h[n] = cy;
}

__global__ __launch_bounds__(256) void scatter2_packed(
    const int* __restrict__ h_id, const int* __restrict__ t_id,
    const float* __restrict__ dde1, const float* __restrict__ dde3,
    u64* __restrict__ acc2_t, u64* __restrict__ acc2_h, int E)
{
    int e = blockIdx.x * 256 + threadIdx.x;
    if (e >= E) return;
    int h = h_id[e], t = t_id[e];
    float2 v1 = *(const float2*)(dde1 + 2 * h);
    float2 v3 = *(const float2*)(dde3 + 2 * t);
    const float sc = 1048576.0f;  // 2^20
    u64 p2 = (u64)__float2uint_rn(v1.x * sc)
           | ((u64)__float2uint_rn(v1.y * sc) << 32);
    u64 p4 = (u64)__float2uint_rn(v3.x * sc)
           | ((u64)__float2uint_rn(v3.y * sc) << 32);
    atomicAdd(&acc2_t[t], p2);
    atomicAdd(&acc2_h[h], p4);
}

__global__ __launch_bounds__(256) void unpack2(
    const u64* __restrict__ acc2_t, const u64* __restrict__ acc2_h,
    const float* __restrict__ cnt_t, const float* __restrict__ cnt_h,
    float* __restrict__ dde2, float* __restrict__ dde4, int N)
{
    int n = blockIdx.x * 256 + threadIdx.x;
    if (n >= N) return;
    const float is = 1.0f / 1048576.0f;
    u64 a = acc2_t[n];
    float ia = is / fmaxf(cnt_t[n], 1.0f);
    dde2[2 * n + 0] = (float)(a & 0xFFFFFFFFull) * ia;
    dde2[2 * n + 1] = (float)(a >> 32) * ia;
    u64 b = acc2_h[n];
    float ib = is / fmaxf(cnt_h[n], 1.0f);
    dde4[2 * n + 0] = (float)(b & 0xFFFFFFFFull) * ib;
    dde4[2 * n + 1] = (float)(b >> 32) * ib;
}

// ---------------------------------------------------------------------------
// WTQ[k][j] = W1[j, k] ; WTR[k][j] = W1[j, 266+k]   (for qr_pre, coalesced)
// ---------------------------------------------------------------------------

__global__ __launch_bounds__(256) void wt_prep(
    const float* __restrict__ W1, float* __restrict__ WTQ,
    float* __restrict__ WTR)
{
    int k = blockIdx.x, t = threadIdx.x;
    if (t < 128) WTQ[(size_t)k * 128 + t] = W1[(size_t)t * W1LD + k];
    else         WTR[(size_t)k * 128 + (t - 128)] =
                     W1[(size_t)(t - 128) * W1LD + 266 + k];
}

// ---------------------------------------------------------------------------
// WBF: bf16 weights in MFMA B-fragment order.
// Logical Wfull[k][n] (k<138): n<128 -> W1[n, 128+k] (h-side),
//                              n>=128 -> W1[n-128, 394+k] (t-side); 0 for k>=138.
// Layout: WBF[((kstep*4 + quad)*256 + n)*8 + j], k = kstep*32 + quad*8 + j.
// ---------------------------------------------------------------------------

__global__ __launch_bounds__(256) void wbf_prep(
    const float* __restrict__ W1, unsigned short* __restrict__ WBF)
{
    int k = blockIdx.x;        // 0..159
    int n = threadIdx.x;       // 0..255
    float v = 0.0f;
    if (k < 138) {
        v = (n < 128) ? W1[(size_t)n * W1LD + 128 + k]
                      : W1[(size_t)(n - 128) * W1LD + 394 + k];
    }
    int kstep = k >> 5, quad = (k >> 3) & 3, j = k & 7;
    WBF[(((size_t)(kstep * 4 + quad) * 256 + n) << 3) + j] = f2bf(v);
}

// ---------------------------------------------------------------------------
// qWb / R precompute
// ---------------------------------------------------------------------------

__global__ __launch_bounds__(128) void qr_pre(
    const float* __restrict__ q, const float* __restrict__ rel,
    const float* __restrict__ WTQ, const float* __restrict__ WTR,
    const float* __restrict__ b1,
    float* __restrict__ qWb, float* __restrict__ R, int NREL)
{
    __shared__ float v[EMB];
    int j = threadIdx.x;
    int b = blockIdx.x;
    const float* src = (b == 0) ? q   : rel + (size_t)(b - 1) * EMB;
    const float* wt  = (b == 0) ? WTQ : WTR;
    float* dst       = (b == 0) ? qWb : R + (size_t)(b - 1) * EMB;
    v[j] = src[j];
    __syncthreads();
    float s = 0.0f;
#pragma unroll 4
    for (int k = 0; k < EMB; k++) s += v[k] * wt[(size_t)k * 128 + j];
    if (b == 0) s += b1[j];
    dst[j] = s;
}

// ---------------------------------------------------------------------------
// Node kernel v3 (MFMA): [32 nodes x 160] @ [160 x 256] in bf16 -> f32 acc.
// 4 waves/block: wave w -> rows m0 = (w&1)*16, cols n0 = (w>>1)*128 (8 tiles).
// a-frag from LDS-staged bf16 features (1 ds_read_b128 per kstep, reused
// across 8 n-tiles); b-frag from WBF global (coalesced 16B/lane, L1/L2-hot).
// D layout: col = lane&15, row = quad*4 + reg (verified mapping).
// ---------------------------------------------------------------------------

__global__ __launch_bounds__(256) void node_ab(
    const float* __restrict__ ent, const float* __restrict__ nte,
    const float* __restrict__ topic, const float* __restrict__ dde,
    const unsigned short* __restrict__ WBF, const float* __restrict__ qWb,
    unsigned short* __restrict__ A, unsigned short* __restrict__ B,
    int NT, int N)
{
    __shared__ __align__(16) unsigned short fsb[32][KP];
    const int t    = threadIdx.x;
    const int lane = t & 63;
    const int w    = t >> 6;
    const int ln15 = lane & 15;
    const int quad = lane >> 4;
    const int m0   = (w & 1) * 16;
    const int n0   = (w >> 1) * 128;
    const int nblk = blockIdx.x * 32;

    // ---- stage dense features as bf16: thread -> node m = t>>3, 16 k-elems ----
    {
        int m  = t >> 3;
        int kq = (t & 7) << 4;     // 0,16,...,112
        int gn = nblk + m;
        const float* src = (gn < N) ? ((gn < NT) ? ent + (size_t)gn * EMB + kq
                                                 : nte + kq)
                                    : nte;  // dummy (guarded below)
        unsigned short pk[16];
#pragma unroll
        for (int p = 0; p < 4; p++) {
            float4 v = (gn < N) ? *(const float4*)(src + 4 * p)
                                : make_float4(0.f, 0.f, 0.f, 0.f);
            pk[4 * p + 0] = f2bf(v.x); pk[4 * p + 1] = f2bf(v.y);
            pk[4 * p + 2] = f2bf(v.z); pk[4 * p + 3] = f2bf(v.w);
        }
        *(uint4*)&fsb[m][kq]     = *(uint4*)&pk[0];
        *(uint4*)&fsb[m][kq + 8] = *(uint4*)&pk[8];
    }
    // ---- tail features k=128..137 ----
    for (int i = t; i < 320; i += 256) {
        int m  = i / 10;
        int mm = i - m * 10;
        int gn = nblk + m;
        float v = 0.0f;
        if (gn < N) {
            if (mm < 2) v = topic[2 * gn + mm];
            else {
                int d = mm - 2;
                v = dde[(size_t)(d >> 1) * 2 * N + 2 * gn + (d & 1)];
            }
        }
        fsb[m][EMB + mm] = f2bf(v);
    }
    // ---- zero pad k=138..159 ----
    for (int i = t; i < 32 * 22; i += 256) {
        int m = i / 22, z = i - m * 22;
        fsb[m][138 + z] = 0;
    }
    __syncthreads();

    f32x4 acc[8];
#pragma unroll
    for (int i = 0; i < 8; i++) acc[i] = (f32x4){0.f, 0.f, 0.f, 0.f};

    const unsigned short* wbbase = WBF + (((size_t)quad * 256 + n0 + ln15) << 3);
#pragma unroll
    for (int ks = 0; ks < 5; ks++) {
        short8 a = *(const short8*)&fsb[m0 + ln15][ks * 32 + quad * 8];
        const unsigned short* wb = wbbase + ((size_t)ks * 4 * 256 * 8);
#pragma unroll
        for (int nt = 0; nt < 8; nt++) {
            short8 b = *(const short8*)(wb + (nt << 7));  // +16 cols * 8
            acc[nt] = __builtin_amdgcn_mfma_f32_16x16x32_bf16(a, b, acc[nt], 0, 0, 0);
        }
    }

    // ---- epilogue: D[row=quad*4+r][col=ln15 within tile] ----
    const int colbase = n0 + ln15;
    if (n0 == 0) {
#pragma unroll
        for (int nt = 0; nt < 8; nt++) {
            int c = colbase + nt * 16;
            float qv = qWb[c];
#pragma unroll
            for (int r = 0; r < 4; r++) {
                int gn = nblk + m0 + quad * 4 + r;
                if (gn < N) A[(size_t)gn * EMB + c] = f2bf(acc[nt][r] + qv);
            }
        }
    } else {
#pragma unroll
        for (int nt = 0; nt < 8; nt++) {
            int c = colbase + nt * 16 - 128;
#pragma unroll
            for (int r = 0; r < 4; r++) {
                int gn = nblk + m0 + quad * 4 + r;
                if (gn < N) B[(size_t)gn * EMB + c] = f2bf(acc[nt][r]);
            }
        }
    }
}

// ---------------------------------------------------------------------------
// Edge kernel: 16 lanes per edge, 8 elems/lane, 4 edges/wave.
// pred[e] = W2 . relu(A[h] + R[r] + B[t]) + b2
// ---------------------------------------------------------------------------

__global__ __launch_bounds__(256) void edge_pred(
    const int* __restrict__ h_id, const int* __restrict__ r_id,
    const int* __restrict__ t_id,
    const unsigned short* __restrict__ A, const unsigned short* __restrict__ B,
    const float* __restrict__ R,
    const float* __restrict__ W2, const float* __restrict__ b2,
    float* __restrict__ out, int E)
{
    const int t    = threadIdx.x;
    const int lane = t & 63;
    const int g    = lane >> 4;
    const int k    = lane & 15;
    const int wv   = t >> 6;
    const int e    = blockIdx.x * 16 + wv * 4 + g;

    const float4 w0 = *(const float4*)(W2 + k * 8);
    const float4 w1 = *(const float4*)(W2 + k * 8 + 4);

    float s = 0.0f;
    if (e < E) {
        const int h = h_id[e], r = r_id[e], tt = t_id[e];
        const uint4  ua = *(const uint4*)(A + (size_t)h * EMB + k * 8);
        const uint4  ub = *(const uint4*)(B + (size_t)tt * EMB + k * 8);
        const float* rp = R + (size_t)r * EMB + k * 8;
        const float4 r0 = *(const float4*)(rp);
        const float4 r1 = *(const float4*)(rp + 4);

        float a0 = __uint_as_float(ua.x << 16), a1 = __uint_as_float(ua.x & 0xffff0000u);
        float a2 = __uint_as_float(ua.y << 16), a3 = __uint_as_float(ua.y & 0xffff0000u);
        float a4 = __uint_as_float(ua.z << 16), a5 = __uint_as_float(ua.z & 0xffff0000u);
        float a6 = __uint_as_float(ua.w << 16), a7 = __uint_as_float(ua.w & 0xffff0000u);
        float c0 = __uint_as_float(ub.x << 16), c1 = __uint_as_float(ub.x & 0xffff0000u);
        float c2 = __uint_as_float(ub.y << 16), c3 = __uint_as_float(ub.y & 0xffff0000u);
        float c4 = __uint_as_float(ub.z << 16), c5 = __uint_as_float(ub.z & 0xffff0000u);
        float c6 = __uint_as_float(ub.w << 16), c7 = __uint_as_float(ub.w & 0xffff0000u);

        s  = fmaxf(a0 + r0.x + c0, 0.0f) * w0.x;
        s += fmaxf(a1 + r0.y + c1, 0.0f) * w0.y;
        s += fmaxf(a2 + r0.z + c2, 0.0f) * w0.z;
        s += fmaxf(a3 + r0.w + c3, 0.0f) * w0.w;
        s += fmaxf(a4 + r1.x + c4, 0.0f) * w1.x;
        s += fmaxf(a5 + r1.y + c5, 0.0f) * w1.y;
        s += fmaxf(a6 + r1.z + c6, 0.0f) * w1.z;
        s += fmaxf(a7 + r1.w + c7, 0.0f) * w1.w;
    }
    s += __shfl_xor(s, 1, 64);
    s += __shfl_xor(s, 2, 64);
    s += __shfl_xor(s, 4, 64);
    s += __shfl_xor(s, 8, 64);
    if (k == 0 && e < E) out[e] = s + b2[0];
}

// ---------------------------------------------------------------------------

extern "C" void kernel_launch(void* const* d_in, const int* in_sizes, int n_in,
                              void* d_out, int out_size, void* d_ws, size_t ws_size,
                              hipStream_t stream)
{
    const int*   h_id  = (const int*)d_in[0];
    const int*   r_id  = (const int*)d_in[1];
    const int*   t_id  = (const int*)d_in[2];
    const float* q_emb = (const float*)d_in[3];
    const float* ent   = (const float*)d_in[4];
    const float* rel   = (const float*)d_in[6];
    const float* topic = (const float*)d_in[7];
    const float* nte   = (const float*)d_in[8];
    const float* W1    = (const float*)d_in[9];
    const float* b1    = (const float*)d_in[10];
    const float* W2    = (const float*)d_in[11];
    const float* b2    = (const float*)d_in[12];

    const int E    = in_sizes[0];
    const int NT   = in_sizes[4] / EMB;  // 80000 text entities
    const int N    = in_sizes[7] / 2;    // 100000 total nodes
    const int NREL = in_sizes[6] / EMB;  // 500 relations

    // workspace layout
    u64* acc1_t = (u64*)d_ws;                 // N u64
    u64* acc1_h = acc1_t + N;                 // N u64
    u64* acc2_t = acc1_h + N;                 // N u64
    u64* acc2_h = acc2_t + N;                 // N u64
    float* cnt_t = (float*)(acc2_h + N);      // N
    float* cnt_h = cnt_t + N;                 // N
    float* dde   = cnt_h + N;                 // 8N (dde1..4, 2N each)
    float* dde1  = dde + (size_t)0 * 2 * N;
    float* dde2  = dde + (size_t)1 * 2 * N;
    float* dde3  = dde + (size_t)2 * 2 * N;
    float* dde4  = dde + (size_t)3 * 2 * N;
    float* qWb   = dde + (size_t)8 * N;       // 128
    float* Rw    = qWb + EMB;                 // NREL*128
    float* WTQ   = Rw + (size_t)NREL * EMB;   // 128*128
    float* WTR   = WTQ + 128 * 128;           // 128*128
    unsigned short* WBF = (unsigned short*)(WTR + 128 * 128); // 160*256 bf16
    unsigned short* Aw  = WBF + (size_t)KP * 256;             // N*128 bf16
    unsigned short* Bw  = Aw + (size_t)N * EMB;               // N*128 bf16

    // zero only the packed atomic accumulators (4N u64)
    hipMemsetAsync(d_ws, 0, sizeof(u64) * (size_t)(4 * N), stream);

    const int tb = 256;
    scatter1_packed<<<(E + tb - 1) / tb, tb, 0, stream>>>(
        h_id, t_id, topic, acc1_t, acc1_h, E);
    unpack1<<<(N + tb - 1) / tb, tb, 0, stream>>>(
        acc1_t, acc1_h, dde1, dde3, cnt_t, cnt_h, N);
    scatter2_packed<<<(E + tb - 1) / tb, tb, 0, stream>>>(
        h_id, t_id, dde1, dde3, acc2_t, acc2_h, E);
    unpack2<<<(N + tb - 1) / tb, tb, 0, stream>>>(
        acc2_t, acc2_h, cnt_t, cnt_h, dde2, dde4, N);

    wt_prep<<<128, 256, 0, stream>>>(W1, WTQ, WTR);
    wbf_prep<<<KP, 256, 0, stream>>>(W1, WBF);
    qr_pre<<<NREL + 1, 128, 0, stream>>>(q_emb, rel, WTQ, WTR, b1, qWb, Rw, NREL);

    node_ab<<<(N + 31) / 32, 256, 0, stream>>>(ent, nte, topic, dde, WBF, qWb,
                                               Aw, Bw, NT, N);

    edge_pred<<<(E + 15) / 16, 256, 0, stream>>>(h_id, r_id, t_id, Aw, Bw, Rw,
                                                 W2, b2, (float*)d_out, E);
}

// Round 8
// 349.434 us; speedup vs baseline: 2.8687x; 1.0399x over previous
//
#include <hip/hip_runtime.h>

#define EMB 128
#define W1LD 532  // PRED_IN
#define KP 160    // padded K for MFMA (138 -> 160)
#define ST 264    // LDS row stride (u16) in node_ab: 132 words, banks spread

typedef unsigned long long u64;
typedef unsigned short u16;
typedef __attribute__((ext_vector_type(8))) short short8;
typedef __attribute__((ext_vector_type(4))) float f32x4;

// bf16 round-to-nearest-even
__device__ __forceinline__ u16 f2bf(float x) {
    unsigned u = __float_as_uint(x);
    unsigned r = (u + 0x7fffu + ((u >> 16) & 1u)) >> 16;
    return (u16)r;
}
__device__ __forceinline__ float bf2f_lo(unsigned u) { return __uint_as_float(u << 16); }
__device__ __forceinline__ float bf2f_hi(unsigned u) { return __uint_as_float(u & 0xffff0000u); }

// ---------------------------------------------------------------------------
// DDE scatter-mean via packed u64 atomics (atomic-transaction-floor: 2/edge).
// Round 1 pack: [x*2^13 : 21b][y*2^13 : 21b][count : 22b]
// Round 2 pack: [x*2^20 : 32b][y*2^20 : 32b]  (count reused from round 1)
// ---------------------------------------------------------------------------

__global__ __launch_bounds__(256) void scatter1_packed(
    const int* __restrict__ h_id, const int* __restrict__ t_id,
    const float* __restrict__ topic,
    u64* __restrict__ acc_t, u64* __restrict__ acc_h, int E)
{
    int e = blockIdx.x * 256 + threadIdx.x;
    if (e >= E) return;
    int h = h_id[e], t = t_id[e];
    float2 th = *(const float2*)(topic + 2 * h);
    float2 tt = *(const float2*)(topic + 2 * t);
    u64 p1 = (u64)__float2uint_rn(th.x * 8192.0f)
           | ((u64)__float2uint_rn(th.y * 8192.0f) << 21)
           | (1ull << 42);
    u64 p3 = (u64)__float2uint_rn(tt.x * 8192.0f)
           | ((u64)__float2uint_rn(tt.y * 8192.0f) << 21)
           | (1ull << 42);
    atomicAdd(&acc_t[t], p1);
    atomicAdd(&acc_h[h], p3);
}

// round-1 mean, unpacked inline from the packed accumulator
__device__ __forceinline__ float2 unpack1_mean(u64 a) {
    float c = (float)(unsigned)(a >> 42);
    float inv = (1.0f / 8192.0f) / fmaxf(c, 1.0f);
    float2 v;
    v.x = (float)(unsigned)(a & 0x1FFFFFull) * inv;
    v.y = (float)(unsigned)((a >> 21) & 0x1FFFFFull) * inv;
    return v;
}

__global__ __launch_bounds__(256) void scatter2_fused(
    const int* __restrict__ h_id, const int* __restrict__ t_id,
    const u64* __restrict__ acc1_t, const u64* __restrict__ acc1_h,
    u64* __restrict__ acc2_t, u64* __restrict__ acc2_h, int E)
{
    int e = blockIdx.x * 256 + threadIdx.x;
    if (e >= E) return;
    int h = h_id[e], t = t_id[e];
    float2 v1 = unpack1_mean(acc1_t[h]);   // dde1[h]
    float2 v3 = unpack1_mean(acc1_h[t]);   // dde3[t]
    const float sc = 1048576.0f;  // 2^20
    u64 p2 = (u64)__float2uint_rn(v1.x * sc)
           | ((u64)__float2uint_rn(v1.y * sc) << 32);
    u64 p4 = (u64)__float2uint_rn(v3.x * sc)
           | ((u64)__float2uint_rn(v3.y * sc) << 32);
    atomicAdd(&acc2_t[t], p2);
    atomicAdd(&acc2_h[h], p4);
}

// ---------------------------------------------------------------------------
// Fused prep:
//  blocks 0..159    : WBF row k=bid (bf16 MFMA B-fragment order)
//  blocks 160..160+NREL : b=bid-160; b==0 -> qWb (f32), else Rbf row (bf16)
// WBF logical Wfull[k][n]: n<128 -> W1[n,128+k] (h-side), n>=128 -> W1[n-128,394+k]
// Layout: WBF[((kstep*4+quad)*256+n)*8 + j], k = kstep*32 + quad*8 + j.
// ---------------------------------------------------------------------------

__global__ __launch_bounds__(256) void prep(
    const float* __restrict__ W1, const float* __restrict__ q,
    const float* __restrict__ rel, const float* __restrict__ b1,
    u16* __restrict__ WBF, float* __restrict__ qWb,
    u16* __restrict__ Rbf, int NREL)
{
    int bid = blockIdx.x, t = threadIdx.x;
    if (bid < KP) {
        int k = bid, n = t;
        float v = 0.0f;
        if (k < 138) {
            v = (n < 128) ? W1[(size_t)n * W1LD + 128 + k]
                          : W1[(size_t)(n - 128) * W1LD + 394 + k];
        }
        int kstep = k >> 5, quad = (k >> 3) & 3, j = k & 7;
        WBF[(((size_t)(kstep * 4 + quad) * 256 + n) << 3) + j] = f2bf(v);
        return;
    }
    int b = bid - KP;   // 0 -> qWb ; 1..NREL -> relation b-1
    __shared__ float v[EMB];
    if (t < EMB) v[t] = (b == 0) ? q[t] : rel[(size_t)(b - 1) * EMB + t];
    __syncthreads();
    if (t < EMB) {
        const float* w = W1 + (size_t)t * W1LD + (b == 0 ? 0 : 266);
        float s = 0.0f;
#pragma unroll
        for (int k = 0; k < EMB; k += 4) {
            float4 wv = *(const float4*)(w + k);
            s += wv.x * v[k] + wv.y * v[k + 1] + wv.z * v[k + 2] + wv.w * v[k + 3];
        }
        if (b == 0) qWb[t] = s + b1[t];
        else        Rbf[(size_t)(b - 1) * EMB + t] = f2bf(s);
    }
}

// ---------------------------------------------------------------------------
// Node kernel (MFMA): [32 nodes x 160] @ [160 x 256] bf16 -> f32 acc.
// 4 waves/block: wave w -> rows m0=(w&1)*16, cols n0=(w>>1)*128 (8 tiles).
// Tail features unpacked inline from packed accumulators (no dde arrays).
// Epilogue: LDS transpose (stride ST) -> 4 coalesced uint4 stores/thread.
// ---------------------------------------------------------------------------

__global__ __launch_bounds__(256) void node_ab(
    const float* __restrict__ ent, const float* __restrict__ nte,
    const float* __restrict__ topic,
    const u64* __restrict__ acc1_t, const u64* __restrict__ acc1_h,
    const u64* __restrict__ acc2_t, const u64* __restrict__ acc2_h,
    const u16* __restrict__ WBF, const float* __restrict__ qWb,
    u16* __restrict__ A, u16* __restrict__ B,
    int NT, int N)
{
    __shared__ __align__(16) u16 lds[32 * ST];
    const int t    = threadIdx.x;
    const int lane = t & 63;
    const int w    = t >> 6;
    const int ln15 = lane & 15;
    const int quad = lane >> 4;
    const int m0   = (w & 1) * 16;
    const int n0   = (w >> 1) * 128;
    const int nblk = blockIdx.x * 32;

    // ---- stage dense features as bf16: thread -> node m=t>>3, 16 k-elems ----
    {
        int m  = t >> 3;
        int kq = (t & 7) << 4;     // 0,16,...,112
        int gn = nblk + m;
        const float* src = (gn < N) ? ((gn < NT) ? ent + (size_t)gn * EMB + kq
                                                 : nte + kq)
                                    : nte;
        u16 pk[16];
#pragma unroll
        for (int p = 0; p < 4; p++) {
            float4 v = (gn < N) ? *(const float4*)(src + 4 * p)
                                : make_float4(0.f, 0.f, 0.f, 0.f);
            pk[4 * p + 0] = f2bf(v.x); pk[4 * p + 1] = f2bf(v.y);
            pk[4 * p + 2] = f2bf(v.z); pk[4 * p + 3] = f2bf(v.w);
        }
        *(uint4*)&lds[m * ST + kq]     = *(uint4*)&pk[0];
        *(uint4*)&lds[m * ST + kq + 8] = *(uint4*)&pk[8];
    }
    // ---- tail features k=128..137 (topic + dde1..4 inline-unpacked) + pad ----
    if (t < 32) {
        int gn = nblk + t;
        float vals[10];
#pragma unroll
        for (int i = 0; i < 10; i++) vals[i] = 0.0f;
        if (gn < N) {
            float2 tp = *(const float2*)(topic + 2 * gn);
            vals[0] = tp.x; vals[1] = tp.y;
            u64 a1 = acc1_t[gn];
            u64 b1v = acc1_h[gn];
            float2 d1 = unpack1_mean(a1);   // dde1
            float2 d3 = unpack1_mean(b1v);  // dde3
            float c1 = (float)(unsigned)(a1 >> 42);
            float c2 = (float)(unsigned)(b1v >> 42);
            const float is20 = 1.0f / 1048576.0f;
            float i1 = is20 / fmaxf(c1, 1.0f);
            float i2 = is20 / fmaxf(c2, 1.0f);
            u64 a2 = acc2_t[gn];
            u64 b2v = acc2_h[gn];
            vals[2] = d1.x; vals[3] = d1.y;
            vals[4] = (float)(unsigned)(a2 & 0xFFFFFFFFull) * i1;   // dde2
            vals[5] = (float)(unsigned)(a2 >> 32) * i1;
            vals[6] = d3.x; vals[7] = d3.y;
            vals[8] = (float)(unsigned)(b2v & 0xFFFFFFFFull) * i2;  // dde4
            vals[9] = (float)(unsigned)(b2v >> 32) * i2;
        }
#pragma unroll
        for (int i = 0; i < 10; i++) lds[t * ST + EMB + i] = f2bf(vals[i]);
#pragma unroll
        for (int z = 138; z < KP; z++) lds[t * ST + z] = 0;
    }
    __syncthreads();

    f32x4 acc[8];
#pragma unroll
    for (int i = 0; i < 8; i++) acc[i] = (f32x4){0.f, 0.f, 0.f, 0.f};

    const u16* wbbase = WBF + (((size_t)quad * 256 + n0 + ln15) << 3);
#pragma unroll
    for (int ks = 0; ks < 5; ks++) {
        short8 a = *(const short8*)&lds[(m0 + ln15) * ST + ks * 32 + quad * 8];
        const u16* wb = wbbase + ((size_t)ks * 4 * 256 * 8);
#pragma unroll
        for (int nt = 0; nt < 8; nt++) {
            short8 b = *(const short8*)(wb + (nt << 7));
            acc[nt] = __builtin_amdgcn_mfma_f32_16x16x32_bf16(a, b, acc[nt], 0, 0, 0);
        }
    }

    // ---- epilogue: transpose through LDS, then coalesced uint4 stores ----
    __syncthreads();   // all a-frag reads done before overwrite
#pragma unroll
    for (int nt = 0; nt < 8; nt++) {
        int c = n0 + nt * 16 + ln15;
        float qv = (n0 == 0) ? qWb[c] : 0.0f;
#pragma unroll
        for (int r = 0; r < 4; r++) {
            int row = m0 + quad * 4 + r;
            lds[row * ST + c] = f2bf(acc[nt][r] + qv);
        }
    }
    __syncthreads();
    {
        int m  = t >> 3;
        int c0 = (t & 7) * 32;
        int gn = nblk + m;
        if (gn < N) {
            uint4 v0 = *(uint4*)&lds[m * ST + c0];
            uint4 v1 = *(uint4*)&lds[m * ST + c0 + 8];
            uint4 v2 = *(uint4*)&lds[m * ST + c0 + 16];
            uint4 v3 = *(uint4*)&lds[m * ST + c0 + 24];
            u16* dst = (c0 < 128) ? (A + (size_t)gn * EMB + c0)
                                  : (B + (size_t)gn * EMB + (c0 - 128));
            ((uint4*)dst)[0] = v0;
            ((uint4*)dst)[1] = v1;
            ((uint4*)dst)[2] = v2;
            ((uint4*)dst)[3] = v3;
        }
    }
}

// ---------------------------------------------------------------------------
// Edge kernel: 16 lanes/edge, 8 elems/lane, 4 edges/wave. All gathers uint4.
// pred[e] = W2 . relu(A[h] + R[r] + B[t]) + b2
// ---------------------------------------------------------------------------

__global__ __launch_bounds__(256) void edge_pred(
    const int* __restrict__ h_id, const int* __restrict__ r_id,
    const int* __restrict__ t_id,
    const u16* __restrict__ A, const u16* __restrict__ B,
    const u16* __restrict__ Rbf,
    const float* __restrict__ W2, const float* __restrict__ b2,
    float* __restrict__ out, int E)
{
    const int t    = threadIdx.x;
    const int lane = t & 63;
    const int g    = lane >> 4;
    const int k    = lane & 15;
    const int wv   = t >> 6;
    const int e    = blockIdx.x * 16 + wv * 4 + g;

    const float4 w0 = *(const float4*)(W2 + k * 8);
    const float4 w1 = *(const float4*)(W2 + k * 8 + 4);

    float s = 0.0f;
    if (e < E) {
        const int h = h_id[e], r = r_id[e], tt = t_id[e];
        const uint4 ua = *(const uint4*)(A + (size_t)h * EMB + k * 8);
        const uint4 ub = *(const uint4*)(B + (size_t)tt * EMB + k * 8);
        const uint4 ur = *(const uint4*)(Rbf + (size_t)r * EMB + k * 8);

        s  = fmaxf(bf2f_lo(ua.x) + bf2f_lo(ur.x) + bf2f_lo(ub.x), 0.0f) * w0.x;
        s += fmaxf(bf2f_hi(ua.x) + bf2f_hi(ur.x) + bf2f_hi(ub.x), 0.0f) * w0.y;
        s += fmaxf(bf2f_lo(ua.y) + bf2f_lo(ur.y) + bf2f_lo(ub.y), 0.0f) * w0.z;
        s += fmaxf(bf2f_hi(ua.y) + bf2f_hi(ur.y) + bf2f_hi(ub.y), 0.0f) * w0.w;
        s += fmaxf(bf2f_lo(ua.z) + bf2f_lo(ur.z) + bf2f_lo(ub.z), 0.0f) * w1.x;
        s += fmaxf(bf2f_hi(ua.z) + bf2f_hi(ur.z) + bf2f_hi(ub.z), 0.0f) * w1.y;
        s += fmaxf(bf2f_lo(ua.w) + bf2f_lo(ur.w) + bf2f_lo(ub.w), 0.0f) * w1.z;
        s += fmaxf(bf2f_hi(ua.w) + bf2f_hi(ur.w) + bf2f_hi(ub.w), 0.0f) * w1.w;
    }
    s += __shfl_xor(s, 1, 64);
    s += __shfl_xor(s, 2, 64);
    s += __shfl_xor(s, 4, 64);
    s += __shfl_xor(s, 8, 64);
    if (k == 0 && e < E) out[e] = s + b2[0];
}

// ---------------------------------------------------------------------------

extern "C" void kernel_launch(void* const* d_in, const int* in_sizes, int n_in,
                              void* d_out, int out_size, void* d_ws, size_t ws_size,
                              hipStream_t stream)
{
    const int*   h_id  = (const int*)d_in[0];
    const int*   r_id  = (const int*)d_in[1];
    const int*   t_id  = (const int*)d_in[2];
    const float* q_emb = (const float*)d_in[3];
    const float* ent   = (const float*)d_in[4];
    const float* rel   = (const float*)d_in[6];
    const float* topic = (const float*)d_in[7];
    const float* nte   = (const float*)d_in[8];
    const float* W1    = (const float*)d_in[9];
    const float* b1    = (const float*)d_in[10];
    const float* W2    = (const float*)d_in[11];
    const float* b2    = (const float*)d_in[12];

    const int E    = in_sizes[0];
    const int NT   = in_sizes[4] / EMB;  // 80000 text entities
    const int N    = in_sizes[7] / 2;    // 100000 total nodes
    const int NREL = in_sizes[6] / EMB;  // 500 relations

    // workspace layout
    u64* acc1_t = (u64*)d_ws;                 // N
    u64* acc1_h = acc1_t + N;                 // N
    u64* acc2_t = acc1_h + N;                 // N
    u64* acc2_h = acc2_t + N;                 // N   (memset region: 4N u64)
    float* qWb  = (float*)(acc2_h + N);       // 128
    u16* Rbf    = (u16*)(qWb + EMB);          // NREL*128 bf16
    u16* WBF    = Rbf + (size_t)NREL * EMB;   // 160*256 bf16
    u16* Aw     = WBF + (size_t)KP * 256;     // N*128 bf16
    u16* Bw     = Aw + (size_t)N * EMB;       // N*128 bf16

    hipMemsetAsync(d_ws, 0, sizeof(u64) * (size_t)(4 * N), stream);

    const int tb = 256;
    scatter1_packed<<<(E + tb - 1) / tb, tb, 0, stream>>>(
        h_id, t_id, topic, acc1_t, acc1_h, E);
    scatter2_fused<<<(E + tb - 1) / tb, tb, 0, stream>>>(
        h_id, t_id, acc1_t, acc1_h, acc2_t, acc2_h, E);

    prep<<<KP + 1 + NREL, tb, 0, stream>>>(W1, q_emb, rel, b1,
                                           WBF, qWb, Rbf, NREL);

    node_ab<<<(N + 31) / 32, tb, 0, stream>>>(
        ent, nte, topic, acc1_t, acc1_h, acc2_t, acc2_h,
        WBF, qWb, Aw, Bw, NT, N);

    edge_pred<<<(E + 15) / 16, tb, 0, stream>>>(h_id, r_id, t_id, Aw, Bw, Rbf,
                                                W2, b2, (float*)d_out, E);
}